// Round 10
// baseline (428.849 us; speedup 1.0000x reference)
//
#include <hip/hip_runtime.h>
#include <hip/hip_bf16.h>
#include <cstdint>
#include <cstddef>

// Problem constants
#define B_  2
#define S_  4096
#define D_  512
#define H_  8
#define HD_ 64
#define QSCALE_ 0.18033688f   // 0.125 * log2(e): scores come out in exp2 domain

typedef short s16x8 __attribute__((ext_vector_type(8)));
typedef float f32x4 __attribute__((ext_vector_type(4)));

__device__ __forceinline__ unsigned short f2bf(float f) {
    unsigned u = __builtin_bit_cast(unsigned, f);
    u += 0x7fffu + ((u >> 16) & 1u);   // round-to-nearest-even (finite values only)
    return (unsigned short)(u >> 16);
}

__device__ __forceinline__ unsigned packbf2(float a, float b) {
    unsigned r;
    asm("v_cvt_pk_bf16_f32 %0, %1, %2" : "=v"(r) : "v"(a), "v"(b));
    return r;
}

// async global->LDS, 16B per lane; dst must be wave-uniform base (lane*16 added by HW)
__device__ __forceinline__ void gload16(const unsigned short* g, unsigned short* l) {
    __builtin_amdgcn_global_load_lds(
        (const __attribute__((address_space(1))) void*)g,
        (__attribute__((address_space(3))) void*)l,
        16, 0, 0);
}

// 64-row x 128B tile, swizzle ((row&7)<<4) — used for both K and V tiles
__device__ __forceinline__ s16x8 kfr(const unsigned short* buf, int kr, int hb) {
    return *(const s16x8*)((const char*)buf + kr * 128 + (hb ^ ((kr & 7) << 4)));
}

// ---------------------------------------------------------------------------
// Kernel 1: cast + transpose the four weight matrices to bf16, wt[n][k]
// ---------------------------------------------------------------------------
__global__ __launch_bounds__(256)
void prep_weights(const float* __restrict__ wq, const float* __restrict__ wk,
                  const float* __restrict__ wv, const float* __restrict__ wo,
                  unsigned short* __restrict__ wt) {
    int e = blockIdx.x * 256 + threadIdx.x;      // 4 * 512 * 512 total
    int mat = e >> 18;
    int i = e & 262143;
    int n = i >> 9, k = i & 511;
    const float* w = (mat == 0) ? wq : (mat == 1) ? wk : (mat == 2) ? wv : wo;
    wt[(size_t)mat * 262144 + n * 512 + k] = f2bf(w[k * 512 + n]);
}

// ---------------------------------------------------------------------------
// Kernel 2a: fused Q/K/V projection GEMM (blockIdx.z selects matrix).
//   z=0: Q (scale QSCALE_, [t][c] bf16)   z=1: K ([t][c] bf16)
//   z=2: V (head-transposed [b][h][hd][s] bf16, LDS-staged transposed store)
// ---------------------------------------------------------------------------
__global__ __launch_bounds__(256)
void qkv_gemm(const float* __restrict__ qx, const float* __restrict__ kx,
              const float* __restrict__ vx, const unsigned short* __restrict__ wtb,
              const float* __restrict__ bqp, const float* __restrict__ bkp,
              const float* __restrict__ bvp,
              unsigned short* __restrict__ qo, unsigned short* __restrict__ ko,
              unsigned short* __restrict__ vo) {
    __shared__ unsigned short xs[64 * 72];
    __shared__ unsigned short wsd[64 * 72];

    const int z = blockIdx.z;
    const float* xin = (z == 0) ? qx : (z == 1) ? kx : vx;
    const unsigned short* wt = wtb + (size_t)z * 262144;
    const float* bias = (z == 0) ? bqp : (z == 1) ? bkp : bvp;
    const float oscale = (z == 0) ? QSCALE_ : 1.0f;

    const int tid  = threadIdx.x;
    const int wave = tid >> 6, lane = tid & 63;
    const int l15 = lane & 15, l4 = lane >> 4;
    const int row0 = blockIdx.x * 64, col0 = blockIdx.y * 64;
    const int sr = tid >> 2, seg = tid & 3;

    f32x4 acc[4] = {};

    for (int kt = 0; kt < 512; kt += 64) {
        {
            const float* x = xin + (size_t)(row0 + sr) * 512 + kt + seg * 16;
            unsigned short tmp[16];
            #pragma unroll
            for (int j = 0; j < 16; j += 4) {
                float4 v = *(const float4*)(x + j);
                tmp[j] = f2bf(v.x); tmp[j+1] = f2bf(v.y); tmp[j+2] = f2bf(v.z); tmp[j+3] = f2bf(v.w);
            }
            *(s16x8*)&xs[sr * 72 + seg * 16]     = *(s16x8*)&tmp[0];
            *(s16x8*)&xs[sr * 72 + seg * 16 + 8] = *(s16x8*)&tmp[8];
        }
        {
            const unsigned short* wp = wt + (size_t)(col0 + sr) * 512 + kt + seg * 16;
            *(s16x8*)&wsd[sr * 72 + seg * 16]     = *(const s16x8*)(wp);
            *(s16x8*)&wsd[sr * 72 + seg * 16 + 8] = *(const s16x8*)(wp + 8);
        }
        __syncthreads();

        #pragma unroll
        for (int ks = 0; ks < 2; ++ks) {
            s16x8 a = *(const s16x8*)&xs[(wave * 16 + l15) * 72 + ks * 32 + l4 * 8];
            #pragma unroll
            for (int ng = 0; ng < 4; ++ng) {
                s16x8 b = *(const s16x8*)&wsd[(ng * 16 + l15) * 72 + ks * 32 + l4 * 8];
                acc[ng] = __builtin_amdgcn_mfma_f32_16x16x32_bf16(a, b, acc[ng], 0, 0, 0);
            }
        }
        __syncthreads();
    }

    if (z == 2) {
        // stage transposed tile in LDS, then contiguous stores along s
        #pragma unroll
        for (int ng = 0; ng < 4; ++ng) {
            float bv = bias[col0 + ng * 16 + l15];
            #pragma unroll
            for (int r = 0; r < 4; ++r)
                xs[(ng * 16 + l15) * 72 + wave * 16 + l4 * 4 + r] = f2bf(acc[ng][r] + bv);
        }
        __syncthreads();
        const int bb = row0 >> 12, s0l = row0 & 4095, hh = col0 >> 6;
        unsigned short* dst = vo + ((size_t)(bb * H_ + hh) * HD_ + sr) * S_ + s0l + seg * 16;
        *(s16x8*)dst       = *(const s16x8*)&xs[sr * 72 + seg * 16];
        *(s16x8*)(dst + 8) = *(const s16x8*)&xs[sr * 72 + seg * 16 + 8];
    } else {
        unsigned short* out = (z == 0) ? qo : ko;
        #pragma unroll
        for (int ng = 0; ng < 4; ++ng) {
            int c = col0 + ng * 16 + l15;
            float bv = bias[c];
            #pragma unroll
            for (int r = 0; r < 4; ++r) {
                int t = row0 + wave * 16 + l4 * 4 + r;
                out[(size_t)t * 512 + c] = f2bf((acc[ng][r] + bv) * oscale);
            }
        }
    }
}

// ---------------------------------------------------------------------------
// Kernel 2b: output projection GEMM (bf16 in, fp32 out)
// ---------------------------------------------------------------------------
__global__ __launch_bounds__(256)
void oproj_gemm(const unsigned short* __restrict__ xin, const unsigned short* __restrict__ wt,
                const float* __restrict__ bias, float* __restrict__ out) {
    __shared__ unsigned short xs[64 * 72];
    __shared__ unsigned short wsd[64 * 72];

    const int tid  = threadIdx.x;
    const int wave = tid >> 6, lane = tid & 63;
    const int l15 = lane & 15, l4 = lane >> 4;
    const int row0 = blockIdx.x * 64, col0 = blockIdx.y * 64;
    const int sr = tid >> 2, seg = tid & 3;

    f32x4 acc[4] = {};

    for (int kt = 0; kt < 512; kt += 64) {
        {
            const unsigned short* x = xin + (size_t)(row0 + sr) * 512 + kt + seg * 16;
            *(s16x8*)&xs[sr * 72 + seg * 16]     = *(const s16x8*)(x);
            *(s16x8*)&xs[sr * 72 + seg * 16 + 8] = *(const s16x8*)(x + 8);
        }
        {
            const unsigned short* wp = wt + (size_t)(col0 + sr) * 512 + kt + seg * 16;
            *(s16x8*)&wsd[sr * 72 + seg * 16]     = *(const s16x8*)(wp);
            *(s16x8*)&wsd[sr * 72 + seg * 16 + 8] = *(const s16x8*)(wp + 8);
        }
        __syncthreads();

        #pragma unroll
        for (int ks = 0; ks < 2; ++ks) {
            s16x8 a = *(const s16x8*)&xs[(wave * 16 + l15) * 72 + ks * 32 + l4 * 8];
            #pragma unroll
            for (int ng = 0; ng < 4; ++ng) {
                s16x8 b = *(const s16x8*)&wsd[(ng * 16 + l15) * 72 + ks * 32 + l4 * 8];
                acc[ng] = __builtin_amdgcn_mfma_f32_16x16x32_bf16(a, b, acc[ng], 0, 0, 0);
            }
        }
        __syncthreads();
    }

    #pragma unroll
    for (int ng = 0; ng < 4; ++ng) {
        int c = col0 + ng * 16 + l15;
        float bv = bias[c];
        #pragma unroll
        for (int r = 0; r < 4; ++r) {
            int t = row0 + wave * 16 + l4 * 4 + r;
            out[(size_t)t * 512 + c] = acc[ng][r] + bv;
        }
    }
}

// ---------------------------------------------------------------------------
// Kernel 3: fused attention (R8-proven two-pass flow), KVBLK=64 double-
// buffered -> LDS 48KB -> 3 blocks/CU (launch_bounds caps VGPR for 3).
// Pass 1: per-lane exp2 denom (in-register). Pass 2: normalized P, plain
// f32x4 weight stores, PV. s_setprio around MFMA clusters.
// ---------------------------------------------------------------------------
__global__ __launch_bounds__(256, 3)
void attn_kernel(const unsigned short* __restrict__ qb,
                 const unsigned short* __restrict__ kb,
                 const unsigned short* __restrict__ vt,
                 float* __restrict__ wout,          // weights tensor base [B,H,S,S]
                 unsigned short* __restrict__ ob) { // pre-projection output, bf16 [t][512]
    __shared__ unsigned short kbuf[2][4096];   // 64 keys x 64 hd (128B rows, swizzled)
    __shared__ unsigned short vbuf[2][4096];   // 64 hd x 64 keys (128B rows, swizzled)
    __shared__ unsigned short pstrip[4][2048]; // per-wave 32q x 64k bf16 (swizzled)

    const int tid  = threadIdx.x;
    const int wave = tid >> 6, lane = tid & 63;
    const int l15 = lane & 15, l4 = lane >> 4;

    // XCD-aware swizzle (512 blocks, bijective)
    const int lid = blockIdx.x;
    const int wid = (lid & 7) * 64 + (lid >> 3);
    const int bh = wid >> 5;
    const int q0 = (wid & 31) * 128;
    const int b = bh >> 3, h = bh & 7;

    // staging coords (identical pattern for K and V: 8 rows/gload, 128B rows)
    const int srow = lane >> 3;                   // 0..7
    const int scol = 8 * ((lane & 7) ^ srow);     // pre-swizzled source col (elems)
    const unsigned short* kstg0 = kb + (size_t)(b * S_ + wave * 16 + srow) * 512 + h * 64 + scol;
    const unsigned short* vstg0 = vt + ((size_t)bh * HD_ + wave * 16 + srow) * S_ + scol;

#define KSTAGE(c, bsel)                                                         \
    { _Pragma("unroll")                                                         \
      for (int i_ = 0; i_ < 2; ++i_)                                            \
          gload16(kstg0 + ((size_t)(c) * 64 + i_ * 8) * 512,                    \
                  &kbuf[bsel][(wave * 16 + i_ * 8) * 64]); }

#define VSTAGE(c, bsel)                                                         \
    { _Pragma("unroll")                                                         \
      for (int i_ = 0; i_ < 2; ++i_)                                            \
          gload16(vstg0 + (size_t)i_ * 8 * 4096 + (c) * 64,                     \
                  &vbuf[bsel][(wave * 16 + i_ * 8) * 64]); }

    // Q fragments: 2 q-halves x 2 k-halves (pre-scaled by 0.125*log2e)
    s16x8 aq[2][2];
    #pragma unroll
    for (int qh = 0; qh < 2; ++qh) {
        const int t = b * S_ + q0 + wave * 32 + qh * 16 + l15;
        const unsigned short* qp = qb + (size_t)t * 512 + h * 64;
        aq[qh][0] = *(const s16x8*)(qp + l4 * 8);
        aq[qh][1] = *(const s16x8*)(qp + 32 + l4 * 8);
    }

    // ---------------- pass 1: per-lane denominators ----------------
    float lsum[2] = {0.0f, 0.0f};
    KSTAGE(0, 0);
    __syncthreads();

    for (int c = 0; c < 64; ++c) {
        const int cur = c & 1;
        if (c < 63) KSTAGE(c + 1, cur ^ 1);

        f32x4 sc[4][2] = {};
        __builtin_amdgcn_s_setprio(1);
        #pragma unroll
        for (int ks = 0; ks < 2; ++ks)
            #pragma unroll
            for (int kg = 0; kg < 4; ++kg) {
                s16x8 kf = kfr(kbuf[cur], kg * 16 + l15, ks * 64 + l4 * 16);
                sc[kg][0] = __builtin_amdgcn_mfma_f32_16x16x32_bf16(kf, aq[0][ks], sc[kg][0], 0, 0, 0);
                sc[kg][1] = __builtin_amdgcn_mfma_f32_16x16x32_bf16(kf, aq[1][ks], sc[kg][1], 0, 0, 0);
            }
        __builtin_amdgcn_s_setprio(0);
        #pragma unroll
        for (int kg = 0; kg < 4; ++kg)
            #pragma unroll
            for (int r = 0; r < 4; ++r) {
                lsum[0] += __builtin_amdgcn_exp2f(sc[kg][0][r]);
                lsum[1] += __builtin_amdgcn_exp2f(sc[kg][1][r]);
            }
        __syncthreads();
    }

    #pragma unroll
    for (int qh = 0; qh < 2; ++qh) {
        lsum[qh] += __shfl_xor(lsum[qh], 16);
        lsum[qh] += __shfl_xor(lsum[qh], 32);
    }
    const float off[2] = { -__builtin_amdgcn_logf(lsum[0]),
                           -__builtin_amdgcn_logf(lsum[1]) };

    // ---------------- pass 2: weights out + O accumulation ----------------
    f32x4 ao[2][4] = {};
    float* wbase = wout + ((size_t)bh * S_ + q0 + wave * 32) * S_;
    unsigned short* strip = &pstrip[wave][0];

    KSTAGE(0, 0); VSTAGE(0, 0);
    __syncthreads();

    for (int c = 0; c < 64; ++c) {
        const int cur = c & 1;
        if (c < 63) { KSTAGE(c + 1, cur ^ 1); VSTAGE(c + 1, cur ^ 1); }

        f32x4 sc[4][2] = {};
        __builtin_amdgcn_s_setprio(1);
        #pragma unroll
        for (int ks = 0; ks < 2; ++ks)
            #pragma unroll
            for (int kg = 0; kg < 4; ++kg) {
                s16x8 kf = kfr(kbuf[cur], kg * 16 + l15, ks * 64 + l4 * 16);
                sc[kg][0] = __builtin_amdgcn_mfma_f32_16x16x32_bf16(kf, aq[0][ks], sc[kg][0], 0, 0, 0);
                sc[kg][1] = __builtin_amdgcn_mfma_f32_16x16x32_bf16(kf, aq[1][ks], sc[kg][1], 0, 0, 0);
            }
        __builtin_amdgcn_s_setprio(0);

        // normalized weights: plain f32x4 stores + packed bf16 strip
        #pragma unroll
        for (int qh = 0; qh < 2; ++qh) {
            float* wrow = wbase + (size_t)(qh * 16 + l15) * S_ + c * 64;
            const int q = qh * 16 + l15;
            #pragma unroll
            for (int kg = 0; kg < 4; ++kg) {
                f32x4 w;
                #pragma unroll
                for (int r = 0; r < 4; ++r)
                    w[r] = __builtin_amdgcn_exp2f(sc[kg][qh][r] + off[qh]);
                *(f32x4*)(wrow + kg * 16 + l4 * 4) = w;
                uint2 pk;
                pk.x = packbf2(w[0], w[1]);
                pk.y = packbf2(w[2], w[3]);
                *(uint2*)((char*)strip + q * 128 + ((kg * 32 + l4 * 8) ^ ((q & 7) << 4))) = pk;
            }
        }

        // PV: A = P strip frags (wave-private), B = V frags (reused 2x)
        __builtin_amdgcn_s_setprio(1);
        #pragma unroll
        for (int ks = 0; ks < 2; ++ks) {
            s16x8 pa0 = *(const s16x8*)((const char*)strip + l15 * 128
                           + ((ks * 64 + l4 * 16) ^ ((l15 & 7) << 4)));
            s16x8 pa1 = *(const s16x8*)((const char*)strip + (16 + l15) * 128
                           + ((ks * 64 + l4 * 16) ^ ((l15 & 7) << 4)));
            #pragma unroll
            for (int ng = 0; ng < 4; ++ng) {
                s16x8 vf = kfr(vbuf[cur], ng * 16 + l15, ks * 64 + l4 * 16);
                ao[0][ng] = __builtin_amdgcn_mfma_f32_16x16x32_bf16(pa0, vf, ao[0][ng], 0, 0, 0);
                ao[1][ng] = __builtin_amdgcn_mfma_f32_16x16x32_bf16(pa1, vf, ao[1][ng], 0, 0, 0);
            }
        }
        __builtin_amdgcn_s_setprio(0);
        __syncthreads();
    }

    // store O tile (pre-projection) as bf16 [t][512]
    #pragma unroll
    for (int qg = 0; qg < 2; ++qg)
        #pragma unroll
        for (int ng = 0; ng < 4; ++ng) {
            int hd = ng * 16 + l15;
            #pragma unroll
            for (int r = 0; r < 4; ++r) {
                int t = b * S_ + q0 + wave * 32 + qg * 16 + l4 * 4 + r;
                ob[(size_t)t * 512 + h * 64 + hd] = f2bf(ao[qg][ng][r]);
            }
        }
#undef KSTAGE
#undef VSTAGE
}

// ---------------------------------------------------------------------------
// Launch
// ---------------------------------------------------------------------------
extern "C" void kernel_launch(void* const* d_in, const int* in_sizes, int n_in,
                              void* d_out, int out_size, void* d_ws, size_t ws_size,
                              hipStream_t stream) {
    (void)in_sizes; (void)n_in; (void)out_size; (void)ws_size;

    const float* query = (const float*)d_in[0];
    const float* key_  = (const float*)d_in[1];
    const float* value = (const float*)d_in[2];
    const float* wq = (const float*)d_in[3];
    const float* bq = (const float*)d_in[4];
    const float* wk = (const float*)d_in[5];
    const float* bk = (const float*)d_in[6];
    const float* wv = (const float*)d_in[7];
    const float* bv = (const float*)d_in[8];
    const float* wo = (const float*)d_in[9];
    const float* bo = (const float*)d_in[10];
    float* out = (float*)d_out;

    // workspace: wt 2MB | qb 8MB | kb 8MB | vt 8MB | ob 8MB
    char* ws = (char*)d_ws;
    unsigned short* wt = (unsigned short*)(ws);
    unsigned short* qb = (unsigned short*)(ws + 2097152);
    unsigned short* kb = (unsigned short*)(ws + 2097152 + 1 * 8388608);
    unsigned short* vt = (unsigned short*)(ws + 2097152 + 2 * 8388608);
    unsigned short* ob = (unsigned short*)(ws + 2097152 + 3 * 8388608);

    hipLaunchKernelGGL(prep_weights, dim3(4096), dim3(256), 0, stream, wq, wk, wv, wo, wt);

    hipLaunchKernelGGL(qkv_gemm, dim3(128, 8, 3), dim3(256), 0, stream,
                       query, key_, value, wt, bq, bk, bv, qb, kb, vt);

    hipLaunchKernelGGL(attn_kernel, dim3(512), dim3(256), 0, stream,
                       qb, kb, vt, out + 4194304, ob);

    hipLaunchKernelGGL(oproj_gemm, dim3(128, 8), dim3(256), 0, stream,
                       ob, wt + 3 * 262144, bo, out);
}

// Round 11
// 354.724 us; speedup vs baseline: 1.2090x; 1.2090x over previous
//
#include <hip/hip_runtime.h>
#include <hip/hip_bf16.h>
#include <cstdint>
#include <cstddef>

// Problem constants
#define B_  2
#define S_  4096
#define D_  512
#define H_  8
#define HD_ 64
#define QSCALE_ 0.18033688f   // 0.125 * log2(e): scores come out in exp2 domain

typedef short s16x8 __attribute__((ext_vector_type(8)));
typedef float f32x4 __attribute__((ext_vector_type(4)));

__device__ __forceinline__ unsigned short f2bf(float f) {
    unsigned u = __builtin_bit_cast(unsigned, f);
    u += 0x7fffu + ((u >> 16) & 1u);   // round-to-nearest-even (finite values only)
    return (unsigned short)(u >> 16);
}

__device__ __forceinline__ unsigned packbf2(float a, float b) {
    unsigned r;
    asm("v_cvt_pk_bf16_f32 %0, %1, %2" : "=v"(r) : "v"(a), "v"(b));
    return r;
}

// async global->LDS, 16B per lane; dst must be wave-uniform base (lane*16 added by HW)
__device__ __forceinline__ void gload16(const unsigned short* g, const unsigned short* l) {
    __builtin_amdgcn_global_load_lds(
        (const __attribute__((address_space(1))) void*)g,
        (__attribute__((address_space(3))) void*)l,
        16, 0, 0);
}

// K-style tile: rows of 128B, swizzle ((row&7)<<4)
__device__ __forceinline__ s16x8 kfr(const unsigned short* buf, int kr, int hb) {
    return *(const s16x8*)((const char*)buf + kr * 128 + (hb ^ ((kr & 7) << 4)));
}
// V tile: 64 rows x 256B, swizzle ((row&15)<<4)
__device__ __forceinline__ s16x8 vfr_(const unsigned short* buf, int vr, int kbyte) {
    return *(const s16x8*)((const char*)buf + vr * 256 + (kbyte ^ ((vr & 15) << 4)));
}

// ---------------------------------------------------------------------------
// Kernel 1: cast + transpose the four weight matrices to bf16, wt[n][k]
// ---------------------------------------------------------------------------
__global__ __launch_bounds__(256)
void prep_weights(const float* __restrict__ wq, const float* __restrict__ wk,
                  const float* __restrict__ wv, const float* __restrict__ wo,
                  unsigned short* __restrict__ wt) {
    int e = blockIdx.x * 256 + threadIdx.x;      // 4 * 512 * 512 total
    int mat = e >> 18;
    int i = e & 262143;
    int n = i >> 9, k = i & 511;
    const float* w = (mat == 0) ? wq : (mat == 1) ? wk : (mat == 2) ? wv : wo;
    wt[(size_t)mat * 262144 + n * 512 + k] = f2bf(w[k * 512 + n]);
}

// ---------------------------------------------------------------------------
// Kernel 2a: fused Q/K/V projection GEMM (blockIdx.z selects matrix).
//   z=0: Q (scale QSCALE_, [t][c] bf16)   z=1: K ([t][c] bf16)
//   z=2: V (head-transposed [b][h][hd][s] bf16, LDS-staged transposed store)
// ---------------------------------------------------------------------------
__global__ __launch_bounds__(256)
void qkv_gemm(const float* __restrict__ qx, const float* __restrict__ kx,
              const float* __restrict__ vx, const unsigned short* __restrict__ wtb,
              const float* __restrict__ bqp, const float* __restrict__ bkp,
              const float* __restrict__ bvp,
              unsigned short* __restrict__ qo, unsigned short* __restrict__ ko,
              unsigned short* __restrict__ vo) {
    __shared__ unsigned short xs[64 * 72];
    __shared__ unsigned short wsd[64 * 72];

    const int z = blockIdx.z;
    const float* xin = (z == 0) ? qx : (z == 1) ? kx : vx;
    const unsigned short* wt = wtb + (size_t)z * 262144;
    const float* bias = (z == 0) ? bqp : (z == 1) ? bkp : bvp;
    const float oscale = (z == 0) ? QSCALE_ : 1.0f;

    const int tid  = threadIdx.x;
    const int wave = tid >> 6, lane = tid & 63;
    const int l15 = lane & 15, l4 = lane >> 4;
    const int row0 = blockIdx.x * 64, col0 = blockIdx.y * 64;
    const int sr = tid >> 2, seg = tid & 3;

    f32x4 acc[4] = {};

    for (int kt = 0; kt < 512; kt += 64) {
        {
            const float* x = xin + (size_t)(row0 + sr) * 512 + kt + seg * 16;
            unsigned short tmp[16];
            #pragma unroll
            for (int j = 0; j < 16; j += 4) {
                float4 v = *(const float4*)(x + j);
                tmp[j] = f2bf(v.x); tmp[j+1] = f2bf(v.y); tmp[j+2] = f2bf(v.z); tmp[j+3] = f2bf(v.w);
            }
            *(s16x8*)&xs[sr * 72 + seg * 16]     = *(s16x8*)&tmp[0];
            *(s16x8*)&xs[sr * 72 + seg * 16 + 8] = *(s16x8*)&tmp[8];
        }
        {
            const unsigned short* wp = wt + (size_t)(col0 + sr) * 512 + kt + seg * 16;
            *(s16x8*)&wsd[sr * 72 + seg * 16]     = *(const s16x8*)(wp);
            *(s16x8*)&wsd[sr * 72 + seg * 16 + 8] = *(const s16x8*)(wp + 8);
        }
        __syncthreads();

        #pragma unroll
        for (int ks = 0; ks < 2; ++ks) {
            s16x8 a = *(const s16x8*)&xs[(wave * 16 + l15) * 72 + ks * 32 + l4 * 8];
            #pragma unroll
            for (int ng = 0; ng < 4; ++ng) {
                s16x8 b = *(const s16x8*)&wsd[(ng * 16 + l15) * 72 + ks * 32 + l4 * 8];
                acc[ng] = __builtin_amdgcn_mfma_f32_16x16x32_bf16(a, b, acc[ng], 0, 0, 0);
            }
        }
        __syncthreads();
    }

    if (z == 2) {
        // stage transposed tile in LDS, then contiguous stores along s
        #pragma unroll
        for (int ng = 0; ng < 4; ++ng) {
            float bv = bias[col0 + ng * 16 + l15];
            #pragma unroll
            for (int r = 0; r < 4; ++r)
                xs[(ng * 16 + l15) * 72 + wave * 16 + l4 * 4 + r] = f2bf(acc[ng][r] + bv);
        }
        __syncthreads();
        const int bb = row0 >> 12, s0l = row0 & 4095, hh = col0 >> 6;
        unsigned short* dst = vo + ((size_t)(bb * H_ + hh) * HD_ + sr) * S_ + s0l + seg * 16;
        *(s16x8*)dst       = *(const s16x8*)&xs[sr * 72 + seg * 16];
        *(s16x8*)(dst + 8) = *(const s16x8*)&xs[sr * 72 + seg * 16 + 8];
    } else {
        unsigned short* out = (z == 0) ? qo : ko;
        #pragma unroll
        for (int ng = 0; ng < 4; ++ng) {
            int c = col0 + ng * 16 + l15;
            float bv = bias[c];
            #pragma unroll
            for (int r = 0; r < 4; ++r) {
                int t = row0 + wave * 16 + l4 * 4 + r;
                out[(size_t)t * 512 + c] = f2bf((acc[ng][r] + bv) * oscale);
            }
        }
    }
}

// ---------------------------------------------------------------------------
// Kernel 2b: output projection GEMM (bf16 in, fp32 out)
// ---------------------------------------------------------------------------
__global__ __launch_bounds__(256)
void oproj_gemm(const unsigned short* __restrict__ xin, const unsigned short* __restrict__ wt,
                const float* __restrict__ bias, float* __restrict__ out) {
    __shared__ unsigned short xs[64 * 72];
    __shared__ unsigned short wsd[64 * 72];

    const int tid  = threadIdx.x;
    const int wave = tid >> 6, lane = tid & 63;
    const int l15 = lane & 15, l4 = lane >> 4;
    const int row0 = blockIdx.x * 64, col0 = blockIdx.y * 64;
    const int sr = tid >> 2, seg = tid & 3;

    f32x4 acc[4] = {};

    for (int kt = 0; kt < 512; kt += 64) {
        {
            const unsigned short* x = xin + (size_t)(row0 + sr) * 512 + kt + seg * 16;
            *(s16x8*)&xs[sr * 72 + seg * 16]     = *(const s16x8*)(x);
            *(s16x8*)&xs[sr * 72 + seg * 16 + 8] = *(const s16x8*)(x + 8);
        }
        {
            const unsigned short* wp = wt + (size_t)(col0 + sr) * 512 + kt + seg * 16;
            *(s16x8*)&wsd[sr * 72 + seg * 16]     = *(const s16x8*)(wp);
            *(s16x8*)&wsd[sr * 72 + seg * 16 + 8] = *(const s16x8*)(wp + 8);
        }
        __syncthreads();

        #pragma unroll
        for (int ks = 0; ks < 2; ++ks) {
            s16x8 a = *(const s16x8*)&xs[(wave * 16 + l15) * 72 + ks * 32 + l4 * 8];
            #pragma unroll
            for (int ng = 0; ng < 4; ++ng) {
                s16x8 b = *(const s16x8*)&wsd[(ng * 16 + l15) * 72 + ks * 32 + l4 * 8];
                acc[ng] = __builtin_amdgcn_mfma_f32_16x16x32_bf16(a, b, acc[ng], 0, 0, 0);
            }
        }
        __syncthreads();
    }

    #pragma unroll
    for (int ng = 0; ng < 4; ++ng) {
        int c = col0 + ng * 16 + l15;
        float bv = bias[c];
        #pragma unroll
        for (int r = 0; r < 4; ++r) {
            int t = row0 + wave * 16 + l4 * 4 + r;
            out[(size_t)t * 512 + c] = acc[ng][r] + bv;
        }
    }
}

// ---------------------------------------------------------------------------
// Kernel 3: fused attention (R8-proven two-pass flow, unified 80KB smem).
// Pass 1: KVBLK=256 double-buffered (reuses the V/strip space; 16 barriers).
// Pass 2: verbatim R8 (KVBLK=128, plain f32x4 weight stores, setprio, PV).
// ---------------------------------------------------------------------------
__global__ __launch_bounds__(256)
void attn_kernel(const unsigned short* __restrict__ qb,
                 const unsigned short* __restrict__ kb,
                 const unsigned short* __restrict__ vt,
                 float* __restrict__ wout,          // weights tensor base [B,H,S,S]
                 unsigned short* __restrict__ ob) { // pre-projection output, bf16 [t][512]
    __shared__ unsigned short smem[40960];     // 80 KB, manually carved:
    // pass 2: K = smem[0 .. 16383] (2 x 8192), V = smem[16384 .. 32767] (2 x 8192),
    //         P strips = smem[32768 .. 40959] (4 waves x 2048)
    // pass 1: K256 = smem[0 .. 32767] (2 x 16384 = 2 x (256 rows x 64 elems))

    const int tid  = threadIdx.x;
    const int wave = tid >> 6, lane = tid & 63;
    const int l15 = lane & 15, l4 = lane >> 4;

    // XCD-aware swizzle (512 blocks, bijective)
    const int lid = blockIdx.x;
    const int wid = (lid & 7) * 64 + (lid >> 3);
    const int bh = wid >> 5;
    const int q0 = (wid & 31) * 128;
    const int b = bh >> 3, h = bh & 7;

    const int ksrow = lane >> 3;
    const int kscol = 8 * ((lane & 7) ^ ksrow);
    // pass-2 K staging base (wave owns 32 rows per 128-chunk)
    const unsigned short* kstg0 = kb + (size_t)(b * S_ + wave * 32 + ksrow) * 512 + h * 64 + kscol;
    // pass-1 K staging base (wave owns 64 rows per 256-chunk)
    const unsigned short* kstg1 = kb + (size_t)(b * S_ + wave * 64 + ksrow) * 512 + h * 64 + kscol;
    const int vsrow = lane >> 4;

#define KSTAGE1(c, bsel)                                                        \
    { _Pragma("unroll")                                                         \
      for (int i_ = 0; i_ < 8; ++i_)                                            \
          gload16(kstg1 + ((size_t)(c) * 256 + i_ * 8) * 512,                   \
                  smem + (bsel) * 16384 + (wave * 64 + i_ * 8) * 64); }

#define KSTAGE(c, bsel)                                                         \
    { _Pragma("unroll")                                                         \
      for (int i_ = 0; i_ < 4; ++i_)                                            \
          gload16(kstg0 + ((size_t)(c) * 128 + i_ * 8) * 512,                   \
                  smem + (bsel) * 8192 + (wave * 32 + i_ * 8) * 64); }

#define VSTAGE(c, bsel)                                                         \
    { _Pragma("unroll")                                                         \
      for (int i_ = 0; i_ < 4; ++i_) {                                          \
          int vrow_ = wave * 16 + i_ * 4 + vsrow;                               \
          int vcb_  = (lane & 15) ^ (i_ * 4 + vsrow);                           \
          gload16(vt + ((size_t)(bh * 64) + vrow_) * 4096 + (c) * 128 + vcb_ * 8, \
                  smem + 16384 + (bsel) * 8192 + (wave * 16 + i_ * 4) * 128); } }

    // Q fragments: 2 q-halves x 2 k-halves (pre-scaled by 0.125*log2e)
    s16x8 aq[2][2];
    #pragma unroll
    for (int qh = 0; qh < 2; ++qh) {
        const int t = b * S_ + q0 + wave * 32 + qh * 16 + l15;
        const unsigned short* qp = qb + (size_t)t * 512 + h * 64;
        aq[qh][0] = *(const s16x8*)(qp + l4 * 8);
        aq[qh][1] = *(const s16x8*)(qp + 32 + l4 * 8);
    }

    // ---------------- pass 1: per-lane denominators (KVBLK=256) ----------------
    float lsum[2] = {0.0f, 0.0f};
    KSTAGE1(0, 0);
    __syncthreads();

    for (int c = 0; c < 16; ++c) {
        const int cur = c & 1;
        if (c < 15) KSTAGE1(c + 1, cur ^ 1);
        const unsigned short* kcur = smem + cur * 16384;

        #pragma unroll
        for (int sub = 0; sub < 4; ++sub) {
            f32x4 sc[4][2] = {};
            __builtin_amdgcn_s_setprio(1);
            #pragma unroll
            for (int ks = 0; ks < 2; ++ks)
                #pragma unroll
                for (int kg = 0; kg < 4; ++kg) {
                    s16x8 kf = kfr(kcur, sub * 64 + kg * 16 + l15, ks * 64 + l4 * 16);
                    sc[kg][0] = __builtin_amdgcn_mfma_f32_16x16x32_bf16(kf, aq[0][ks], sc[kg][0], 0, 0, 0);
                    sc[kg][1] = __builtin_amdgcn_mfma_f32_16x16x32_bf16(kf, aq[1][ks], sc[kg][1], 0, 0, 0);
                }
            __builtin_amdgcn_s_setprio(0);
            #pragma unroll
            for (int kg = 0; kg < 4; ++kg)
                #pragma unroll
                for (int r = 0; r < 4; ++r) {
                    lsum[0] += __builtin_amdgcn_exp2f(sc[kg][0][r]);
                    lsum[1] += __builtin_amdgcn_exp2f(sc[kg][1][r]);
                }
        }
        __syncthreads();
    }

    #pragma unroll
    for (int qh = 0; qh < 2; ++qh) {
        lsum[qh] += __shfl_xor(lsum[qh], 16);
        lsum[qh] += __shfl_xor(lsum[qh], 32);
    }
    const float off[2] = { -__builtin_amdgcn_logf(lsum[0]),
                           -__builtin_amdgcn_logf(lsum[1]) };

    // ---------------- pass 2: weights out + O accumulation (KVBLK=128) --------
    f32x4 ao[2][4] = {};
    float* wbase = wout + ((size_t)bh * S_ + q0 + wave * 32) * S_;
    unsigned short* strip = smem + 32768 + wave * 2048;

    KSTAGE(0, 0); VSTAGE(0, 0);
    __syncthreads();

    for (int c = 0; c < 32; ++c) {
        const int cur = c & 1;
        if (c < 31) { KSTAGE(c + 1, cur ^ 1); VSTAGE(c + 1, cur ^ 1); }
        const unsigned short* kcur = smem + cur * 8192;
        const unsigned short* vcur = smem + 16384 + cur * 8192;

        #pragma unroll
        for (int sub = 0; sub < 2; ++sub) {
            f32x4 sc[4][2] = {};
            __builtin_amdgcn_s_setprio(1);
            #pragma unroll
            for (int ks = 0; ks < 2; ++ks)
                #pragma unroll
                for (int kg = 0; kg < 4; ++kg) {
                    s16x8 kf = kfr(kcur, sub * 64 + kg * 16 + l15, ks * 64 + l4 * 16);
                    sc[kg][0] = __builtin_amdgcn_mfma_f32_16x16x32_bf16(kf, aq[0][ks], sc[kg][0], 0, 0, 0);
                    sc[kg][1] = __builtin_amdgcn_mfma_f32_16x16x32_bf16(kf, aq[1][ks], sc[kg][1], 0, 0, 0);
                }
            __builtin_amdgcn_s_setprio(0);

            // normalized weights: plain f32x4 stores + packed bf16 strip
            #pragma unroll
            for (int qh = 0; qh < 2; ++qh) {
                float* wrow = wbase + (size_t)(qh * 16 + l15) * S_ + c * 128 + sub * 64;
                const int q = qh * 16 + l15;
                #pragma unroll
                for (int kg = 0; kg < 4; ++kg) {
                    f32x4 w;
                    #pragma unroll
                    for (int r = 0; r < 4; ++r)
                        w[r] = __builtin_amdgcn_exp2f(sc[kg][qh][r] + off[qh]);
                    *(f32x4*)(wrow + kg * 16 + l4 * 4) = w;
                    uint2 pk;
                    pk.x = packbf2(w[0], w[1]);
                    pk.y = packbf2(w[2], w[3]);
                    *(uint2*)((char*)strip + q * 128 + ((kg * 32 + l4 * 8) ^ ((q & 7) << 4))) = pk;
                }
            }

            // PV: A = P strip frags (wave-private), B = V frags (reused 2x)
            __builtin_amdgcn_s_setprio(1);
            #pragma unroll
            for (int ks = 0; ks < 2; ++ks) {
                s16x8 pa0 = *(const s16x8*)((const char*)strip + l15 * 128
                               + ((ks * 64 + l4 * 16) ^ ((l15 & 7) << 4)));
                s16x8 pa1 = *(const s16x8*)((const char*)strip + (16 + l15) * 128
                               + ((ks * 64 + l4 * 16) ^ ((l15 & 7) << 4)));
                #pragma unroll
                for (int ng = 0; ng < 4; ++ng) {
                    s16x8 vf = vfr_(vcur, ng * 16 + l15, sub * 128 + ks * 64 + l4 * 16);
                    ao[0][ng] = __builtin_amdgcn_mfma_f32_16x16x32_bf16(pa0, vf, ao[0][ng], 0, 0, 0);
                    ao[1][ng] = __builtin_amdgcn_mfma_f32_16x16x32_bf16(pa1, vf, ao[1][ng], 0, 0, 0);
                }
            }
            __builtin_amdgcn_s_setprio(0);
        }
        __syncthreads();
    }

    // store O tile (pre-projection) as bf16 [t][512]
    #pragma unroll
    for (int qg = 0; qg < 2; ++qg)
        #pragma unroll
        for (int ng = 0; ng < 4; ++ng) {
            int hd = ng * 16 + l15;
            #pragma unroll
            for (int r = 0; r < 4; ++r) {
                int t = b * S_ + q0 + wave * 32 + qg * 16 + l4 * 4 + r;
                ob[(size_t)t * 512 + h * 64 + hd] = f2bf(ao[qg][ng][r]);
            }
        }
#undef KSTAGE1
#undef KSTAGE
#undef VSTAGE
}

// ---------------------------------------------------------------------------
// Launch
// ---------------------------------------------------------------------------
extern "C" void kernel_launch(void* const* d_in, const int* in_sizes, int n_in,
                              void* d_out, int out_size, void* d_ws, size_t ws_size,
                              hipStream_t stream) {
    (void)in_sizes; (void)n_in; (void)out_size; (void)ws_size;

    const float* query = (const float*)d_in[0];
    const float* key_  = (const float*)d_in[1];
    const float* value = (const float*)d_in[2];
    const float* wq = (const float*)d_in[3];
    const float* bq = (const float*)d_in[4];
    const float* wk = (const float*)d_in[5];
    const float* bk = (const float*)d_in[6];
    const float* wv = (const float*)d_in[7];
    const float* bv = (const float*)d_in[8];
    const float* wo = (const float*)d_in[9];
    const float* bo = (const float*)d_in[10];
    float* out = (float*)d_out;

    // workspace: wt 2MB | qb 8MB | kb 8MB | vt 8MB | ob 8MB
    char* ws = (char*)d_ws;
    unsigned short* wt = (unsigned short*)(ws);
    unsigned short* qb = (unsigned short*)(ws + 2097152);
    unsigned short* kb = (unsigned short*)(ws + 2097152 + 1 * 8388608);
    unsigned short* vt = (unsigned short*)(ws + 2097152 + 2 * 8388608);
    unsigned short* ob = (unsigned short*)(ws + 2097152 + 3 * 8388608);

    hipLaunchKernelGGL(prep_weights, dim3(4096), dim3(256), 0, stream, wq, wk, wv, wo, wt);

    hipLaunchKernelGGL(qkv_gemm, dim3(128, 8, 3), dim3(256), 0, stream,
                       query, key_, value, wt, bq, bk, bv, qb, kb, vt);

    hipLaunchKernelGGL(attn_kernel, dim3(512), dim3(256), 0, stream,
                       qb, kb, vt, out + 4194304, ob);

    hipLaunchKernelGGL(oproj_gemm, dim3(128, 8), dim3(256), 0, stream,
                       ob, wt + 3 * 262144, bo, out);
}

// Round 12
// 350.575 us; speedup vs baseline: 1.2233x; 1.0118x over previous
//
#include <hip/hip_runtime.h>
#include <hip/hip_bf16.h>
#include <cstdint>
#include <cstddef>

// Problem constants
#define B_  2
#define S_  4096
#define D_  512
#define H_  8
#define HD_ 64
#define QSCALE_ 0.18033688f   // 0.125 * log2(e): scores come out in exp2 domain

typedef short s16x8 __attribute__((ext_vector_type(8)));
typedef float f32x4 __attribute__((ext_vector_type(4)));

__device__ __forceinline__ unsigned short f2bf(float f) {
    unsigned u = __builtin_bit_cast(unsigned, f);
    u += 0x7fffu + ((u >> 16) & 1u);   // round-to-nearest-even (finite values only)
    return (unsigned short)(u >> 16);
}

__device__ __forceinline__ unsigned packbf2(float a, float b) {
    unsigned r;
    asm("v_cvt_pk_bf16_f32 %0, %1, %2" : "=v"(r) : "v"(a), "v"(b));
    return r;
}

// async global->LDS, 16B per lane; dst must be wave-uniform base (lane*16 added by HW)
__device__ __forceinline__ void gload16(const unsigned short* g, const unsigned short* l) {
    __builtin_amdgcn_global_load_lds(
        (const __attribute__((address_space(1))) void*)g,
        (__attribute__((address_space(3))) void*)l,
        16, 0, 0);
}

// K-style tile: rows of 128B, swizzle ((row&7)<<4)
__device__ __forceinline__ s16x8 kfr(const unsigned short* buf, int kr, int hb) {
    return *(const s16x8*)((const char*)buf + kr * 128 + (hb ^ ((kr & 7) << 4)));
}
// V tile: 64 rows x 256B, swizzle ((row&15)<<4)
__device__ __forceinline__ s16x8 vfr_(const unsigned short* buf, int vr, int kbyte) {
    return *(const s16x8*)((const char*)buf + vr * 256 + (kbyte ^ ((vr & 15) << 4)));
}

// ---------------------------------------------------------------------------
// Kernel 1: cast + transpose the four weight matrices to bf16, wt[n][k]
// ---------------------------------------------------------------------------
__global__ __launch_bounds__(256)
void prep_weights(const float* __restrict__ wq, const float* __restrict__ wk,
                  const float* __restrict__ wv, const float* __restrict__ wo,
                  unsigned short* __restrict__ wt) {
    int e = blockIdx.x * 256 + threadIdx.x;      // 4 * 512 * 512 total
    int mat = e >> 18;
    int i = e & 262143;
    int n = i >> 9, k = i & 511;
    const float* w = (mat == 0) ? wq : (mat == 1) ? wk : (mat == 2) ? wv : wo;
    wt[(size_t)mat * 262144 + n * 512 + k] = f2bf(w[k * 512 + n]);
}

// ---------------------------------------------------------------------------
// Kernel 2a: fused Q/K/V projection GEMM, 128x128 tile (m93-structure).
// 4 waves, 64x64 per wave (4x4 fragments). BK=64, 8 K-steps, 2 barriers each.
// B (wt bf16) via global_load_lds (pre-swizzled source); A (fp32) reg-staged
// with v_cvt_pk_bf16_f32. z: 0=Q(scaled), 1=K, 2=V (LDS-transposed store).
// ---------------------------------------------------------------------------
__global__ __launch_bounds__(256)
void qkv_gemm(const float* __restrict__ qx, const float* __restrict__ kx,
              const float* __restrict__ vx, const unsigned short* __restrict__ wtb,
              const float* __restrict__ bqp, const float* __restrict__ bkp,
              const float* __restrict__ bvp,
              unsigned short* __restrict__ qo, unsigned short* __restrict__ ko,
              unsigned short* __restrict__ vo) {
    __shared__ unsigned short smem[16384];   // 32KB: A [128][64] | B [128][64] (both swizzled)
    unsigned short* as_ = smem;              // 8192 elems
    unsigned short* bs_ = smem + 8192;

    const int z = blockIdx.z;
    const float* xin = (z == 0) ? qx : (z == 1) ? kx : vx;
    const unsigned short* wt = wtb + (size_t)z * 262144;
    const float* bias = (z == 0) ? bqp : (z == 1) ? bkp : bvp;
    const float oscale = (z == 0) ? QSCALE_ : 1.0f;

    const int tid  = threadIdx.x;
    const int wave = tid >> 6, lane = tid & 63;
    const int l15 = lane & 15, l4 = lane >> 4;
    const int wr = wave >> 1, wc = wave & 1;
    const int row0 = blockIdx.x * 128, col0 = blockIdx.y * 128;

    // A staging: thread t covers row t>>1, 32 fp32 (half = t&1)
    const int arow = tid >> 1, ahalf = tid & 1;
    const float* asrc0 = xin + (size_t)(row0 + arow) * 512 + ahalf * 32;

    // B staging: per-wave 4 gloads of 8 rows, pre-swizzled source column
    const int srow = lane >> 3;
    const int scol = 8 * ((lane & 7) ^ srow);
    const unsigned short* bsrc0 = wt + (size_t)(col0 + wave * 32 + srow) * 512 + scol;

    f32x4 acc[4][4] = {};

    for (int kt = 0; kt < 512; kt += 64) {
        #pragma unroll
        for (int i = 0; i < 4; ++i)
            gload16(bsrc0 + (size_t)i * 8 * 512 + kt, bs_ + (wave * 32 + i * 8) * 64);
        {
            const float* a = asrc0 + kt;
            #pragma unroll
            for (int j = 0; j < 4; ++j) {
                float4 v0 = *(const float4*)(a + j * 8);
                float4 v1 = *(const float4*)(a + j * 8 + 4);
                uint4 pk;
                pk.x = packbf2(v0.x, v0.y); pk.y = packbf2(v0.z, v0.w);
                pk.z = packbf2(v1.x, v1.y); pk.w = packbf2(v1.z, v1.w);
                *(uint4*)((char*)as_ + arow * 128 + ((ahalf * 64 + j * 16) ^ ((arow & 7) << 4))) = pk;
            }
        }
        __syncthreads();

        #pragma unroll
        for (int ks = 0; ks < 2; ++ks) {
            s16x8 af[4], bf[4];
            #pragma unroll
            for (int i = 0; i < 4; ++i) {
                af[i] = kfr(as_, wr * 64 + i * 16 + l15, ks * 64 + l4 * 16);
                bf[i] = kfr(bs_, wc * 64 + i * 16 + l15, ks * 64 + l4 * 16);
            }
            #pragma unroll
            for (int mf = 0; mf < 4; ++mf)
                #pragma unroll
                for (int nf = 0; nf < 4; ++nf)
                    acc[mf][nf] = __builtin_amdgcn_mfma_f32_16x16x32_bf16(af[mf], bf[nf], acc[mf][nf], 0, 0, 0);
        }
        __syncthreads();
    }

    if (z == 2) {
        // transpose-stage into smem: [128 n][128 m] bf16, swizzled rows of 256B
        #pragma unroll
        for (int nf = 0; nf < 4; ++nf) {
            const int nl = wc * 64 + nf * 16 + l15;
            float bv = bias[col0 + nl];
            #pragma unroll
            for (int mf = 0; mf < 4; ++mf) {
                uint2 pk;
                pk.x = packbf2(acc[mf][nf][0] + bv, acc[mf][nf][1] + bv);
                pk.y = packbf2(acc[mf][nf][2] + bv, acc[mf][nf][3] + bv);
                int mb = (wr * 64 + mf * 16 + l4 * 4) * 2;
                *(uint2*)((char*)smem + nl * 256 + (mb ^ ((nl & 7) << 4))) = pk;
            }
        }
        __syncthreads();
        const int nl = tid >> 1, half = tid & 1;
        const int c = col0 + nl, hh = c >> 6, hd = c & 63;
        const int bb = row0 >> 12, s0 = row0 & 4095;
        unsigned short* dst = vo + ((size_t)(bb * H_ + hh) * HD_ + hd) * S_ + s0 + half * 64;
        #pragma unroll
        for (int u = 0; u < 8; ++u)
            *(uint4*)((char*)dst + u * 16) =
                *(const uint4*)((char*)smem + nl * 256 + ((half * 128 + u * 16) ^ ((nl & 7) << 4)));
    } else {
        unsigned short* out = (z == 0) ? qo : ko;
        #pragma unroll
        for (int nf = 0; nf < 4; ++nf) {
            int c = col0 + wc * 64 + nf * 16 + l15;
            float bv = bias[c];
            #pragma unroll
            for (int mf = 0; mf < 4; ++mf)
                #pragma unroll
                for (int r = 0; r < 4; ++r) {
                    int t = row0 + wr * 64 + mf * 16 + l4 * 4 + r;
                    out[(size_t)t * 512 + c] = f2bf((acc[mf][nf][r] + bv) * oscale);
                }
        }
    }
}

// ---------------------------------------------------------------------------
// Kernel 2b: output projection GEMM (bf16 in, fp32 out) — R11-proven 64x64
// ---------------------------------------------------------------------------
__global__ __launch_bounds__(256)
void oproj_gemm(const unsigned short* __restrict__ xin, const unsigned short* __restrict__ wt,
                const float* __restrict__ bias, float* __restrict__ out) {
    __shared__ unsigned short xs[64 * 72];
    __shared__ unsigned short wsd[64 * 72];

    const int tid  = threadIdx.x;
    const int wave = tid >> 6, lane = tid & 63;
    const int l15 = lane & 15, l4 = lane >> 4;
    const int row0 = blockIdx.x * 64, col0 = blockIdx.y * 64;
    const int sr = tid >> 2, seg = tid & 3;

    f32x4 acc[4] = {};

    for (int kt = 0; kt < 512; kt += 64) {
        {
            const unsigned short* x = xin + (size_t)(row0 + sr) * 512 + kt + seg * 16;
            *(s16x8*)&xs[sr * 72 + seg * 16]     = *(const s16x8*)(x);
            *(s16x8*)&xs[sr * 72 + seg * 16 + 8] = *(const s16x8*)(x + 8);
        }
        {
            const unsigned short* wp = wt + (size_t)(col0 + sr) * 512 + kt + seg * 16;
            *(s16x8*)&wsd[sr * 72 + seg * 16]     = *(const s16x8*)(wp);
            *(s16x8*)&wsd[sr * 72 + seg * 16 + 8] = *(const s16x8*)(wp + 8);
        }
        __syncthreads();

        #pragma unroll
        for (int ks = 0; ks < 2; ++ks) {
            s16x8 a = *(const s16x8*)&xs[(wave * 16 + l15) * 72 + ks * 32 + l4 * 8];
            #pragma unroll
            for (int ng = 0; ng < 4; ++ng) {
                s16x8 b = *(const s16x8*)&wsd[(ng * 16 + l15) * 72 + ks * 32 + l4 * 8];
                acc[ng] = __builtin_amdgcn_mfma_f32_16x16x32_bf16(a, b, acc[ng], 0, 0, 0);
            }
        }
        __syncthreads();
    }

    #pragma unroll
    for (int ng = 0; ng < 4; ++ng) {
        int c = col0 + ng * 16 + l15;
        float bv = bias[c];
        #pragma unroll
        for (int r = 0; r < 4; ++r) {
            int t = row0 + wave * 16 + l4 * 4 + r;
            out[(size_t)t * 512 + c] = acc[ng][r] + bv;
        }
    }
}

// ---------------------------------------------------------------------------
// Kernel 3: fused attention (R11-proven two-pass flow, unified 80KB smem).
// Pass 1: KVBLK=256 double-buffered (reuses the V/strip space; 16 barriers).
// Pass 2: KVBLK=128, plain f32x4 weight stores, setprio, PV.
// ---------------------------------------------------------------------------
__global__ __launch_bounds__(256)
void attn_kernel(const unsigned short* __restrict__ qb,
                 const unsigned short* __restrict__ kb,
                 const unsigned short* __restrict__ vt,
                 float* __restrict__ wout,          // weights tensor base [B,H,S,S]
                 unsigned short* __restrict__ ob) { // pre-projection output, bf16 [t][512]
    __shared__ unsigned short smem[40960];     // 80 KB, manually carved:
    // pass 2: K = smem[0 .. 16383] (2 x 8192), V = smem[16384 .. 32767] (2 x 8192),
    //         P strips = smem[32768 .. 40959] (4 waves x 2048)
    // pass 1: K256 = smem[0 .. 32767] (2 x 16384 = 2 x (256 rows x 64 elems))

    const int tid  = threadIdx.x;
    const int wave = tid >> 6, lane = tid & 63;
    const int l15 = lane & 15, l4 = lane >> 4;

    // XCD-aware swizzle (512 blocks, bijective)
    const int lid = blockIdx.x;
    const int wid = (lid & 7) * 64 + (lid >> 3);
    const int bh = wid >> 5;
    const int q0 = (wid & 31) * 128;
    const int b = bh >> 3, h = bh & 7;

    const int ksrow = lane >> 3;
    const int kscol = 8 * ((lane & 7) ^ ksrow);
    // pass-2 K staging base (wave owns 32 rows per 128-chunk)
    const unsigned short* kstg0 = kb + (size_t)(b * S_ + wave * 32 + ksrow) * 512 + h * 64 + kscol;
    // pass-1 K staging base (wave owns 64 rows per 256-chunk)
    const unsigned short* kstg1 = kb + (size_t)(b * S_ + wave * 64 + ksrow) * 512 + h * 64 + kscol;
    const int vsrow = lane >> 4;

#define KSTAGE1(c, bsel)                                                        \
    { _Pragma("unroll")                                                         \
      for (int i_ = 0; i_ < 8; ++i_)                                            \
          gload16(kstg1 + ((size_t)(c) * 256 + i_ * 8) * 512,                   \
                  smem + (bsel) * 16384 + (wave * 64 + i_ * 8) * 64); }

#define KSTAGE(c, bsel)                                                         \
    { _Pragma("unroll")                                                         \
      for (int i_ = 0; i_ < 4; ++i_)                                            \
          gload16(kstg0 + ((size_t)(c) * 128 + i_ * 8) * 512,                   \
                  smem + (bsel) * 8192 + (wave * 32 + i_ * 8) * 64); }

#define VSTAGE(c, bsel)                                                         \
    { _Pragma("unroll")                                                         \
      for (int i_ = 0; i_ < 4; ++i_) {                                          \
          int vrow_ = wave * 16 + i_ * 4 + vsrow;                               \
          int vcb_  = (lane & 15) ^ (i_ * 4 + vsrow);                           \
          gload16(vt + ((size_t)(bh * 64) + vrow_) * 4096 + (c) * 128 + vcb_ * 8, \
                  smem + 16384 + (bsel) * 8192 + (wave * 16 + i_ * 4) * 128); } }

    // Q fragments: 2 q-halves x 2 k-halves (pre-scaled by 0.125*log2e)
    s16x8 aq[2][2];
    #pragma unroll
    for (int qh = 0; qh < 2; ++qh) {
        const int t = b * S_ + q0 + wave * 32 + qh * 16 + l15;
        const unsigned short* qp = qb + (size_t)t * 512 + h * 64;
        aq[qh][0] = *(const s16x8*)(qp + l4 * 8);
        aq[qh][1] = *(const s16x8*)(qp + 32 + l4 * 8);
    }

    // ---------------- pass 1: per-lane denominators (KVBLK=256) ----------------
    float lsum[2] = {0.0f, 0.0f};
    KSTAGE1(0, 0);
    __syncthreads();

    for (int c = 0; c < 16; ++c) {
        const int cur = c & 1;
        if (c < 15) KSTAGE1(c + 1, cur ^ 1);
        const unsigned short* kcur = smem + cur * 16384;

        #pragma unroll
        for (int sub = 0; sub < 4; ++sub) {
            f32x4 sc[4][2] = {};
            __builtin_amdgcn_s_setprio(1);
            #pragma unroll
            for (int ks = 0; ks < 2; ++ks)
                #pragma unroll
                for (int kg = 0; kg < 4; ++kg) {
                    s16x8 kf = kfr(kcur, sub * 64 + kg * 16 + l15, ks * 64 + l4 * 16);
                    sc[kg][0] = __builtin_amdgcn_mfma_f32_16x16x32_bf16(kf, aq[0][ks], sc[kg][0], 0, 0, 0);
                    sc[kg][1] = __builtin_amdgcn_mfma_f32_16x16x32_bf16(kf, aq[1][ks], sc[kg][1], 0, 0, 0);
                }
            __builtin_amdgcn_s_setprio(0);
            #pragma unroll
            for (int kg = 0; kg < 4; ++kg)
                #pragma unroll
                for (int r = 0; r < 4; ++r) {
                    lsum[0] += __builtin_amdgcn_exp2f(sc[kg][0][r]);
                    lsum[1] += __builtin_amdgcn_exp2f(sc[kg][1][r]);
                }
        }
        __syncthreads();
    }

    #pragma unroll
    for (int qh = 0; qh < 2; ++qh) {
        lsum[qh] += __shfl_xor(lsum[qh], 16);
        lsum[qh] += __shfl_xor(lsum[qh], 32);
    }
    const float off[2] = { -__builtin_amdgcn_logf(lsum[0]),
                           -__builtin_amdgcn_logf(lsum[1]) };

    // ---------------- pass 2: weights out + O accumulation (KVBLK=128) --------
    f32x4 ao[2][4] = {};
    float* wbase = wout + ((size_t)bh * S_ + q0 + wave * 32) * S_;
    unsigned short* strip = smem + 32768 + wave * 2048;

    KSTAGE(0, 0); VSTAGE(0, 0);
    __syncthreads();

    for (int c = 0; c < 32; ++c) {
        const int cur = c & 1;
        if (c < 31) { KSTAGE(c + 1, cur ^ 1); VSTAGE(c + 1, cur ^ 1); }
        const unsigned short* kcur = smem + cur * 8192;
        const unsigned short* vcur = smem + 16384 + cur * 8192;

        #pragma unroll
        for (int sub = 0; sub < 2; ++sub) {
            f32x4 sc[4][2] = {};
            __builtin_amdgcn_s_setprio(1);
            #pragma unroll
            for (int ks = 0; ks < 2; ++ks)
                #pragma unroll
                for (int kg = 0; kg < 4; ++kg) {
                    s16x8 kf = kfr(kcur, sub * 64 + kg * 16 + l15, ks * 64 + l4 * 16);
                    sc[kg][0] = __builtin_amdgcn_mfma_f32_16x16x32_bf16(kf, aq[0][ks], sc[kg][0], 0, 0, 0);
                    sc[kg][1] = __builtin_amdgcn_mfma_f32_16x16x32_bf16(kf, aq[1][ks], sc[kg][1], 0, 0, 0);
                }
            __builtin_amdgcn_s_setprio(0);

            // normalized weights: plain f32x4 stores + packed bf16 strip
            #pragma unroll
            for (int qh = 0; qh < 2; ++qh) {
                float* wrow = wbase + (size_t)(qh * 16 + l15) * S_ + c * 128 + sub * 64;
                const int q = qh * 16 + l15;
                #pragma unroll
                for (int kg = 0; kg < 4; ++kg) {
                    f32x4 w;
                    #pragma unroll
                    for (int r = 0; r < 4; ++r)
                        w[r] = __builtin_amdgcn_exp2f(sc[kg][qh][r] + off[qh]);
                    *(f32x4*)(wrow + kg * 16 + l4 * 4) = w;
                    uint2 pk;
                    pk.x = packbf2(w[0], w[1]);
                    pk.y = packbf2(w[2], w[3]);
                    *(uint2*)((char*)strip + q * 128 + ((kg * 32 + l4 * 8) ^ ((q & 7) << 4))) = pk;
                }
            }

            // PV: A = P strip frags (wave-private), B = V frags (reused 2x)
            __builtin_amdgcn_s_setprio(1);
            #pragma unroll
            for (int ks = 0; ks < 2; ++ks) {
                s16x8 pa0 = *(const s16x8*)((const char*)strip + l15 * 128
                               + ((ks * 64 + l4 * 16) ^ ((l15 & 7) << 4)));
                s16x8 pa1 = *(const s16x8*)((const char*)strip + (16 + l15) * 128
                               + ((ks * 64 + l4 * 16) ^ ((l15 & 7) << 4)));
                #pragma unroll
                for (int ng = 0; ng < 4; ++ng) {
                    s16x8 vf = vfr_(vcur, ng * 16 + l15, sub * 128 + ks * 64 + l4 * 16);
                    ao[0][ng] = __builtin_amdgcn_mfma_f32_16x16x32_bf16(pa0, vf, ao[0][ng], 0, 0, 0);
                    ao[1][ng] = __builtin_amdgcn_mfma_f32_16x16x32_bf16(pa1, vf, ao[1][ng], 0, 0, 0);
                }
            }
            __builtin_amdgcn_s_setprio(0);
        }
        __syncthreads();
    }

    // store O tile (pre-projection) as bf16 [t][512]
    #pragma unroll
    for (int qg = 0; qg < 2; ++qg)
        #pragma unroll
        for (int ng = 0; ng < 4; ++ng) {
            int hd = ng * 16 + l15;
            #pragma unroll
            for (int r = 0; r < 4; ++r) {
                int t = b * S_ + q0 + wave * 32 + qg * 16 + l4 * 4 + r;
                ob[(size_t)t * 512 + h * 64 + hd] = f2bf(ao[qg][ng][r]);
            }
        }
#undef KSTAGE1
#undef KSTAGE
#undef VSTAGE
}

// ---------------------------------------------------------------------------
// Launch
// ---------------------------------------------------------------------------
extern "C" void kernel_launch(void* const* d_in, const int* in_sizes, int n_in,
                              void* d_out, int out_size, void* d_ws, size_t ws_size,
                              hipStream_t stream) {
    (void)in_sizes; (void)n_in; (void)out_size; (void)ws_size;

    const float* query = (const float*)d_in[0];
    const float* key_  = (const float*)d_in[1];
    const float* value = (const float*)d_in[2];
    const float* wq = (const float*)d_in[3];
    const float* bq = (const float*)d_in[4];
    const float* wk = (const float*)d_in[5];
    const float* bk = (const float*)d_in[6];
    const float* wv = (const float*)d_in[7];
    const float* bv = (const float*)d_in[8];
    const float* wo = (const float*)d_in[9];
    const float* bo = (const float*)d_in[10];
    float* out = (float*)d_out;

    // workspace: wt 2MB | qb 8MB | kb 8MB | vt 8MB | ob 8MB
    char* ws = (char*)d_ws;
    unsigned short* wt = (unsigned short*)(ws);
    unsigned short* qb = (unsigned short*)(ws + 2097152);
    unsigned short* kb = (unsigned short*)(ws + 2097152 + 1 * 8388608);
    unsigned short* vt = (unsigned short*)(ws + 2097152 + 2 * 8388608);
    unsigned short* ob = (unsigned short*)(ws + 2097152 + 3 * 8388608);

    hipLaunchKernelGGL(prep_weights, dim3(4096), dim3(256), 0, stream, wq, wk, wv, wo, wt);

    hipLaunchKernelGGL(qkv_gemm, dim3(64, 4, 3), dim3(256), 0, stream,
                       query, key_, value, wt, bq, bk, bv, qb, kb, vt);

    hipLaunchKernelGGL(attn_kernel, dim3(512), dim3(256), 0, stream,
                       qb, kb, vt, out + 4194304, ob);

    hipLaunchKernelGGL(oproj_gemm, dim3(128, 8), dim3(256), 0, stream,
                       ob, wt + 3 * 262144, bo, out);
}

// Round 13
// 347.572 us; speedup vs baseline: 1.2338x; 1.0086x over previous
//
#include <hip/hip_runtime.h>
#include <hip/hip_bf16.h>
#include <cstdint>
#include <cstddef>

// Problem constants
#define B_  2
#define S_  4096
#define D_  512
#define H_  8
#define HD_ 64
#define QSCALE_ 0.18033688f   // 0.125 * log2(e): scores come out in exp2 domain

typedef short s16x8 __attribute__((ext_vector_type(8)));
typedef float f32x4 __attribute__((ext_vector_type(4)));

__device__ __forceinline__ unsigned short f2bf(float f) {
    unsigned u = __builtin_bit_cast(unsigned, f);
    u += 0x7fffu + ((u >> 16) & 1u);   // round-to-nearest-even (finite values only)
    return (unsigned short)(u >> 16);
}

__device__ __forceinline__ unsigned packbf2(float a, float b) {
    unsigned r;
    asm("v_cvt_pk_bf16_f32 %0, %1, %2" : "=v"(r) : "v"(a), "v"(b));
    return r;
}

// async global->LDS, 16B per lane; dst must be wave-uniform base (lane*16 added by HW)
__device__ __forceinline__ void gload16(const unsigned short* g, const unsigned short* l) {
    __builtin_amdgcn_global_load_lds(
        (const __attribute__((address_space(1))) void*)g,
        (__attribute__((address_space(3))) void*)l,
        16, 0, 0);
}

// K-style tile: rows of 128B, swizzle ((row&7)<<4)
__device__ __forceinline__ s16x8 kfr(const unsigned short* buf, int kr, int hb) {
    return *(const s16x8*)((const char*)buf + kr * 128 + (hb ^ ((kr & 7) << 4)));
}
// V tile: 64 rows x 256B, swizzle ((row&15)<<4)
__device__ __forceinline__ s16x8 vfr_(const unsigned short* buf, int vr, int kbyte) {
    return *(const s16x8*)((const char*)buf + vr * 256 + (kbyte ^ ((vr & 15) << 4)));
}

// ---------------------------------------------------------------------------
// Kernel 1: cast + transpose the four weight matrices to bf16, wt[n][k].
// LDS-staged 64x64 tile transpose: coalesced 64B reads, 32B writes.
// Grid: (8, 8, 4) -> 256 blocks of 256 threads.
// ---------------------------------------------------------------------------
__global__ __launch_bounds__(256)
void prep_weights(const float* __restrict__ wq, const float* __restrict__ wk,
                  const float* __restrict__ wv, const float* __restrict__ wo,
                  unsigned short* __restrict__ wt) {
    __shared__ unsigned short ts[64 * 72];   // [k][n] -> read back [n][k], pad 72

    const int mat = blockIdx.z;
    const float* w = (mat == 0) ? wq : (mat == 1) ? wk : (mat == 2) ? wv : wo;
    const int k0 = blockIdx.x * 64, n0 = blockIdx.y * 64;

    const int tid = threadIdx.x;
    const int kr = tid >> 2, nseg = (tid & 3) * 16;   // read: row k0+kr, 16 fp32 along n
    {
        const float* src = w + (size_t)(k0 + kr) * 512 + n0 + nseg;
        unsigned short tmp[16];
        #pragma unroll
        for (int j = 0; j < 16; j += 4) {
            float4 v = *(const float4*)(src + j);
            tmp[j] = f2bf(v.x); tmp[j+1] = f2bf(v.y); tmp[j+2] = f2bf(v.z); tmp[j+3] = f2bf(v.w);
        }
        #pragma unroll
        for (int j = 0; j < 16; ++j)
            ts[(nseg + j) * 72 + kr] = tmp[j];   // transpose into LDS
    }
    __syncthreads();

    const int nr = tid >> 2, kseg = (tid & 3) * 16;  // write: row n0+nr, 16 bf16 along k
    unsigned short* dst = wt + (size_t)mat * 262144 + (size_t)(n0 + nr) * 512 + k0 + kseg;
    *(s16x8*)dst       = *(const s16x8*)&ts[nr * 72 + kseg];
    *(s16x8*)(dst + 8) = *(const s16x8*)&ts[nr * 72 + kseg + 8];
}

// ---------------------------------------------------------------------------
// Kernel 2a: fused Q/K/V projection GEMM, 128x128 tile (R12-proven).
// ---------------------------------------------------------------------------
__global__ __launch_bounds__(256)
void qkv_gemm(const float* __restrict__ qx, const float* __restrict__ kx,
              const float* __restrict__ vx, const unsigned short* __restrict__ wtb,
              const float* __restrict__ bqp, const float* __restrict__ bkp,
              const float* __restrict__ bvp,
              unsigned short* __restrict__ qo, unsigned short* __restrict__ ko,
              unsigned short* __restrict__ vo) {
    __shared__ unsigned short smem[16384];   // 32KB: A [128][64] | B [128][64] (both swizzled)
    unsigned short* as_ = smem;              // 8192 elems
    unsigned short* bs_ = smem + 8192;

    const int z = blockIdx.z;
    const float* xin = (z == 0) ? qx : (z == 1) ? kx : vx;
    const unsigned short* wt = wtb + (size_t)z * 262144;
    const float* bias = (z == 0) ? bqp : (z == 1) ? bkp : bvp;
    const float oscale = (z == 0) ? QSCALE_ : 1.0f;

    const int tid  = threadIdx.x;
    const int wave = tid >> 6, lane = tid & 63;
    const int l15 = lane & 15, l4 = lane >> 4;
    const int wr = wave >> 1, wc = wave & 1;
    const int row0 = blockIdx.x * 128, col0 = blockIdx.y * 128;

    // A staging: thread t covers row t>>1, 32 fp32 (half = t&1)
    const int arow = tid >> 1, ahalf = tid & 1;
    const float* asrc0 = xin + (size_t)(row0 + arow) * 512 + ahalf * 32;

    // B staging: per-wave 4 gloads of 8 rows, pre-swizzled source column
    const int srow = lane >> 3;
    const int scol = 8 * ((lane & 7) ^ srow);
    const unsigned short* bsrc0 = wt + (size_t)(col0 + wave * 32 + srow) * 512 + scol;

    f32x4 acc[4][4] = {};

    for (int kt = 0; kt < 512; kt += 64) {
        #pragma unroll
        for (int i = 0; i < 4; ++i)
            gload16(bsrc0 + (size_t)i * 8 * 512 + kt, bs_ + (wave * 32 + i * 8) * 64);
        {
            const float* a = asrc0 + kt;
            #pragma unroll
            for (int j = 0; j < 4; ++j) {
                float4 v0 = *(const float4*)(a + j * 8);
                float4 v1 = *(const float4*)(a + j * 8 + 4);
                uint4 pk;
                pk.x = packbf2(v0.x, v0.y); pk.y = packbf2(v0.z, v0.w);
                pk.z = packbf2(v1.x, v1.y); pk.w = packbf2(v1.z, v1.w);
                *(uint4*)((char*)as_ + arow * 128 + ((ahalf * 64 + j * 16) ^ ((arow & 7) << 4))) = pk;
            }
        }
        __syncthreads();

        #pragma unroll
        for (int ks = 0; ks < 2; ++ks) {
            s16x8 af[4], bf[4];
            #pragma unroll
            for (int i = 0; i < 4; ++i) {
                af[i] = kfr(as_, wr * 64 + i * 16 + l15, ks * 64 + l4 * 16);
                bf[i] = kfr(bs_, wc * 64 + i * 16 + l15, ks * 64 + l4 * 16);
            }
            #pragma unroll
            for (int mf = 0; mf < 4; ++mf)
                #pragma unroll
                for (int nf = 0; nf < 4; ++nf)
                    acc[mf][nf] = __builtin_amdgcn_mfma_f32_16x16x32_bf16(af[mf], bf[nf], acc[mf][nf], 0, 0, 0);
        }
        __syncthreads();
    }

    if (z == 2) {
        // transpose-stage into smem: [128 n][128 m] bf16, swizzled rows of 256B
        #pragma unroll
        for (int nf = 0; nf < 4; ++nf) {
            const int nl = wc * 64 + nf * 16 + l15;
            float bv = bias[col0 + nl];
            #pragma unroll
            for (int mf = 0; mf < 4; ++mf) {
                uint2 pk;
                pk.x = packbf2(acc[mf][nf][0] + bv, acc[mf][nf][1] + bv);
                pk.y = packbf2(acc[mf][nf][2] + bv, acc[mf][nf][3] + bv);
                int mb = (wr * 64 + mf * 16 + l4 * 4) * 2;
                *(uint2*)((char*)smem + nl * 256 + (mb ^ ((nl & 7) << 4))) = pk;
            }
        }
        __syncthreads();
        const int nl = tid >> 1, half = tid & 1;
        const int c = col0 + nl, hh = c >> 6, hd = c & 63;
        const int bb = row0 >> 12, s0 = row0 & 4095;
        unsigned short* dst = vo + ((size_t)(bb * H_ + hh) * HD_ + hd) * S_ + s0 + half * 64;
        #pragma unroll
        for (int u = 0; u < 8; ++u)
            *(uint4*)((char*)dst + u * 16) =
                *(const uint4*)((char*)smem + nl * 256 + ((half * 128 + u * 16) ^ ((nl & 7) << 4)));
    } else {
        unsigned short* out = (z == 0) ? qo : ko;
        #pragma unroll
        for (int nf = 0; nf < 4; ++nf) {
            int c = col0 + wc * 64 + nf * 16 + l15;
            float bv = bias[c];
            #pragma unroll
            for (int mf = 0; mf < 4; ++mf)
                #pragma unroll
                for (int r = 0; r < 4; ++r) {
                    int t = row0 + wr * 64 + mf * 16 + l4 * 4 + r;
                    out[(size_t)t * 512 + c] = f2bf((acc[mf][nf][r] + bv) * oscale);
                }
        }
    }
}

// ---------------------------------------------------------------------------
// Kernel 2b: output projection GEMM, 128x128 tile (both operands bf16 via
// global_load_lds, pre-swizzled source). fp32 out + bias.
// ---------------------------------------------------------------------------
__global__ __launch_bounds__(256)
void oproj_gemm(const unsigned short* __restrict__ xin, const unsigned short* __restrict__ wt,
                const float* __restrict__ bias, float* __restrict__ out) {
    __shared__ unsigned short smem[16384];   // A [128][64] | B [128][64] swizzled
    unsigned short* as_ = smem;
    unsigned short* bs_ = smem + 8192;

    const int tid  = threadIdx.x;
    const int wave = tid >> 6, lane = tid & 63;
    const int l15 = lane & 15, l4 = lane >> 4;
    const int wr = wave >> 1, wc = wave & 1;
    const int row0 = blockIdx.x * 128, col0 = blockIdx.y * 128;

    const int srow = lane >> 3;
    const int scol = 8 * ((lane & 7) ^ srow);
    const unsigned short* asrc0 = xin + (size_t)(row0 + wave * 32 + srow) * 512 + scol;
    const unsigned short* bsrc0 = wt + (size_t)(col0 + wave * 32 + srow) * 512 + scol;

    f32x4 acc[4][4] = {};

    for (int kt = 0; kt < 512; kt += 64) {
        #pragma unroll
        for (int i = 0; i < 4; ++i) {
            gload16(asrc0 + (size_t)i * 8 * 512 + kt, as_ + (wave * 32 + i * 8) * 64);
            gload16(bsrc0 + (size_t)i * 8 * 512 + kt, bs_ + (wave * 32 + i * 8) * 64);
        }
        __syncthreads();

        #pragma unroll
        for (int ks = 0; ks < 2; ++ks) {
            s16x8 af[4], bf[4];
            #pragma unroll
            for (int i = 0; i < 4; ++i) {
                af[i] = kfr(as_, wr * 64 + i * 16 + l15, ks * 64 + l4 * 16);
                bf[i] = kfr(bs_, wc * 64 + i * 16 + l15, ks * 64 + l4 * 16);
            }
            #pragma unroll
            for (int mf = 0; mf < 4; ++mf)
                #pragma unroll
                for (int nf = 0; nf < 4; ++nf)
                    acc[mf][nf] = __builtin_amdgcn_mfma_f32_16x16x32_bf16(af[mf], bf[nf], acc[mf][nf], 0, 0, 0);
        }
        __syncthreads();
    }

    #pragma unroll
    for (int nf = 0; nf < 4; ++nf) {
        int c = col0 + wc * 64 + nf * 16 + l15;
        float bv = bias[c];
        #pragma unroll
        for (int mf = 0; mf < 4; ++mf)
            #pragma unroll
            for (int r = 0; r < 4; ++r) {
                int t = row0 + wr * 64 + mf * 16 + l4 * 4 + r;
                out[(size_t)t * 512 + c] = acc[mf][nf][r] + bv;
            }
    }
}

// ---------------------------------------------------------------------------
// Kernel 3: fused attention (R11/R12-proven two-pass flow, unified 80KB smem).
// Pass 1: KVBLK=256 double-buffered (reuses the V/strip space; 16 barriers).
// Pass 2: KVBLK=128, plain f32x4 weight stores, setprio, PV.
// ---------------------------------------------------------------------------
__global__ __launch_bounds__(256)
void attn_kernel(const unsigned short* __restrict__ qb,
                 const unsigned short* __restrict__ kb,
                 const unsigned short* __restrict__ vt,
                 float* __restrict__ wout,          // weights tensor base [B,H,S,S]
                 unsigned short* __restrict__ ob) { // pre-projection output, bf16 [t][512]
    __shared__ unsigned short smem[40960];     // 80 KB, manually carved:
    // pass 2: K = smem[0 .. 16383] (2 x 8192), V = smem[16384 .. 32767] (2 x 8192),
    //         P strips = smem[32768 .. 40959] (4 waves x 2048)
    // pass 1: K256 = smem[0 .. 32767] (2 x 16384 = 2 x (256 rows x 64 elems))

    const int tid  = threadIdx.x;
    const int wave = tid >> 6, lane = tid & 63;
    const int l15 = lane & 15, l4 = lane >> 4;

    // XCD-aware swizzle (512 blocks, bijective)
    const int lid = blockIdx.x;
    const int wid = (lid & 7) * 64 + (lid >> 3);
    const int bh = wid >> 5;
    const int q0 = (wid & 31) * 128;
    const int b = bh >> 3, h = bh & 7;

    const int ksrow = lane >> 3;
    const int kscol = 8 * ((lane & 7) ^ ksrow);
    // pass-2 K staging base (wave owns 32 rows per 128-chunk)
    const unsigned short* kstg0 = kb + (size_t)(b * S_ + wave * 32 + ksrow) * 512 + h * 64 + kscol;
    // pass-1 K staging base (wave owns 64 rows per 256-chunk)
    const unsigned short* kstg1 = kb + (size_t)(b * S_ + wave * 64 + ksrow) * 512 + h * 64 + kscol;
    const int vsrow = lane >> 4;

#define KSTAGE1(c, bsel)                                                        \
    { _Pragma("unroll")                                                         \
      for (int i_ = 0; i_ < 8; ++i_)                                            \
          gload16(kstg1 + ((size_t)(c) * 256 + i_ * 8) * 512,                   \
                  smem + (bsel) * 16384 + (wave * 64 + i_ * 8) * 64); }

#define KSTAGE(c, bsel)                                                         \
    { _Pragma("unroll")                                                         \
      for (int i_ = 0; i_ < 4; ++i_)                                            \
          gload16(kstg0 + ((size_t)(c) * 128 + i_ * 8) * 512,                   \
                  smem + (bsel) * 8192 + (wave * 32 + i_ * 8) * 64); }

#define VSTAGE(c, bsel)                                                         \
    { _Pragma("unroll")                                                         \
      for (int i_ = 0; i_ < 4; ++i_) {                                          \
          int vrow_ = wave * 16 + i_ * 4 + vsrow;                               \
          int vcb_  = (lane & 15) ^ (i_ * 4 + vsrow);                           \
          gload16(vt + ((size_t)(bh * 64) + vrow_) * 4096 + (c) * 128 + vcb_ * 8, \
                  smem + 16384 + (bsel) * 8192 + (wave * 16 + i_ * 4) * 128); } }

    // Q fragments: 2 q-halves x 2 k-halves (pre-scaled by 0.125*log2e)
    s16x8 aq[2][2];
    #pragma unroll
    for (int qh = 0; qh < 2; ++qh) {
        const int t = b * S_ + q0 + wave * 32 + qh * 16 + l15;
        const unsigned short* qp = qb + (size_t)t * 512 + h * 64;
        aq[qh][0] = *(const s16x8*)(qp + l4 * 8);
        aq[qh][1] = *(const s16x8*)(qp + 32 + l4 * 8);
    }

    // ---------------- pass 1: per-lane denominators (KVBLK=256) ----------------
    float lsum[2] = {0.0f, 0.0f};
    KSTAGE1(0, 0);
    __syncthreads();

    for (int c = 0; c < 16; ++c) {
        const int cur = c & 1;
        if (c < 15) KSTAGE1(c + 1, cur ^ 1);
        const unsigned short* kcur = smem + cur * 16384;

        #pragma unroll
        for (int sub = 0; sub < 4; ++sub) {
            f32x4 sc[4][2] = {};
            __builtin_amdgcn_s_setprio(1);
            #pragma unroll
            for (int ks = 0; ks < 2; ++ks)
                #pragma unroll
                for (int kg = 0; kg < 4; ++kg) {
                    s16x8 kf = kfr(kcur, sub * 64 + kg * 16 + l15, ks * 64 + l4 * 16);
                    sc[kg][0] = __builtin_amdgcn_mfma_f32_16x16x32_bf16(kf, aq[0][ks], sc[kg][0], 0, 0, 0);
                    sc[kg][1] = __builtin_amdgcn_mfma_f32_16x16x32_bf16(kf, aq[1][ks], sc[kg][1], 0, 0, 0);
                }
            __builtin_amdgcn_s_setprio(0);
            #pragma unroll
            for (int kg = 0; kg < 4; ++kg)
                #pragma unroll
                for (int r = 0; r < 4; ++r) {
                    lsum[0] += __builtin_amdgcn_exp2f(sc[kg][0][r]);
                    lsum[1] += __builtin_amdgcn_exp2f(sc[kg][1][r]);
                }
        }
        __syncthreads();
    }

    #pragma unroll
    for (int qh = 0; qh < 2; ++qh) {
        lsum[qh] += __shfl_xor(lsum[qh], 16);
        lsum[qh] += __shfl_xor(lsum[qh], 32);
    }
    const float off[2] = { -__builtin_amdgcn_logf(lsum[0]),
                           -__builtin_amdgcn_logf(lsum[1]) };

    // ---------------- pass 2: weights out + O accumulation (KVBLK=128) --------
    f32x4 ao[2][4] = {};
    float* wbase = wout + ((size_t)bh * S_ + q0 + wave * 32) * S_;
    unsigned short* strip = smem + 32768 + wave * 2048;

    KSTAGE(0, 0); VSTAGE(0, 0);
    __syncthreads();

    for (int c = 0; c < 32; ++c) {
        const int cur = c & 1;
        if (c < 31) { KSTAGE(c + 1, cur ^ 1); VSTAGE(c + 1, cur ^ 1); }
        const unsigned short* kcur = smem + cur * 8192;
        const unsigned short* vcur = smem + 16384 + cur * 8192;

        #pragma unroll
        for (int sub = 0; sub < 2; ++sub) {
            f32x4 sc[4][2] = {};
            __builtin_amdgcn_s_setprio(1);
            #pragma unroll
            for (int ks = 0; ks < 2; ++ks)
                #pragma unroll
                for (int kg = 0; kg < 4; ++kg) {
                    s16x8 kf = kfr(kcur, sub * 64 + kg * 16 + l15, ks * 64 + l4 * 16);
                    sc[kg][0] = __builtin_amdgcn_mfma_f32_16x16x32_bf16(kf, aq[0][ks], sc[kg][0], 0, 0, 0);
                    sc[kg][1] = __builtin_amdgcn_mfma_f32_16x16x32_bf16(kf, aq[1][ks], sc[kg][1], 0, 0, 0);
                }
            __builtin_amdgcn_s_setprio(0);

            // normalized weights: plain f32x4 stores + packed bf16 strip
            #pragma unroll
            for (int qh = 0; qh < 2; ++qh) {
                float* wrow = wbase + (size_t)(qh * 16 + l15) * S_ + c * 128 + sub * 64;
                const int q = qh * 16 + l15;
                #pragma unroll
                for (int kg = 0; kg < 4; ++kg) {
                    f32x4 w;
                    #pragma unroll
                    for (int r = 0; r < 4; ++r)
                        w[r] = __builtin_amdgcn_exp2f(sc[kg][qh][r] + off[qh]);
                    *(f32x4*)(wrow + kg * 16 + l4 * 4) = w;
                    uint2 pk;
                    pk.x = packbf2(w[0], w[1]);
                    pk.y = packbf2(w[2], w[3]);
                    *(uint2*)((char*)strip + q * 128 + ((kg * 32 + l4 * 8) ^ ((q & 7) << 4))) = pk;
                }
            }

            // PV: A = P strip frags (wave-private), B = V frags (reused 2x)
            __builtin_amdgcn_s_setprio(1);
            #pragma unroll
            for (int ks = 0; ks < 2; ++ks) {
                s16x8 pa0 = *(const s16x8*)((const char*)strip + l15 * 128
                               + ((ks * 64 + l4 * 16) ^ ((l15 & 7) << 4)));
                s16x8 pa1 = *(const s16x8*)((const char*)strip + (16 + l15) * 128
                               + ((ks * 64 + l4 * 16) ^ ((l15 & 7) << 4)));
                #pragma unroll
                for (int ng = 0; ng < 4; ++ng) {
                    s16x8 vf = vfr_(vcur, ng * 16 + l15, sub * 128 + ks * 64 + l4 * 16);
                    ao[0][ng] = __builtin_amdgcn_mfma_f32_16x16x32_bf16(pa0, vf, ao[0][ng], 0, 0, 0);
                    ao[1][ng] = __builtin_amdgcn_mfma_f32_16x16x32_bf16(pa1, vf, ao[1][ng], 0, 0, 0);
                }
            }
            __builtin_amdgcn_s_setprio(0);
        }
        __syncthreads();
    }

    // store O tile (pre-projection) as bf16 [t][512]
    #pragma unroll
    for (int qg = 0; qg < 2; ++qg)
        #pragma unroll
        for (int ng = 0; ng < 4; ++ng) {
            int hd = ng * 16 + l15;
            #pragma unroll
            for (int r = 0; r < 4; ++r) {
                int t = b * S_ + q0 + wave * 32 + qg * 16 + l4 * 4 + r;
                ob[(size_t)t * 512 + h * 64 + hd] = f2bf(ao[qg][ng][r]);
            }
        }
#undef KSTAGE1
#undef KSTAGE
#undef VSTAGE
}

// ---------------------------------------------------------------------------
// Launch
// ---------------------------------------------------------------------------
extern "C" void kernel_launch(void* const* d_in, const int* in_sizes, int n_in,
                              void* d_out, int out_size, void* d_ws, size_t ws_size,
                              hipStream_t stream) {
    (void)in_sizes; (void)n_in; (void)out_size; (void)ws_size;

    const float* query = (const float*)d_in[0];
    const float* key_  = (const float*)d_in[1];
    const float* value = (const float*)d_in[2];
    const float* wq = (const float*)d_in[3];
    const float* bq = (const float*)d_in[4];
    const float* wk = (const float*)d_in[5];
    const float* bk = (const float*)d_in[6];
    const float* wv = (const float*)d_in[7];
    const float* bv = (const float*)d_in[8];
    const float* wo = (const float*)d_in[9];
    const float* bo = (const float*)d_in[10];
    float* out = (float*)d_out;

    // workspace: wt 2MB | qb 8MB | kb 8MB | vt 8MB | ob 8MB
    char* ws = (char*)d_ws;
    unsigned short* wt = (unsigned short*)(ws);
    unsigned short* qb = (unsigned short*)(ws + 2097152);
    unsigned short* kb = (unsigned short*)(ws + 2097152 + 1 * 8388608);
    unsigned short* vt = (unsigned short*)(ws + 2097152 + 2 * 8388608);
    unsigned short* ob = (unsigned short*)(ws + 2097152 + 3 * 8388608);

    hipLaunchKernelGGL(prep_weights, dim3(8, 8, 4), dim3(256), 0, stream, wq, wk, wv, wo, wt);

    hipLaunchKernelGGL(qkv_gemm, dim3(64, 4, 3), dim3(256), 0, stream,
                       query, key_, value, wt, bq, bk, bv, qb, kb, vt);

    hipLaunchKernelGGL(attn_kernel, dim3(512), dim3(256), 0, stream,
                       qb, kb, vt, out + 4194304, ob);

    hipLaunchKernelGGL(oproj_gemm, dim3(64, 4), dim3(256), 0, stream,
                       ob, wt + 3 * 262144, bo, out);
}

// Round 14
// 345.312 us; speedup vs baseline: 1.2419x; 1.0065x over previous
//
#include <hip/hip_runtime.h>
#include <hip/hip_bf16.h>
#include <cstdint>
#include <cstddef>

// Problem constants
#define B_  2
#define S_  4096
#define D_  512
#define H_  8
#define HD_ 64
#define QSCALE_ 0.18033688f   // 0.125 * log2(e): scores come out in exp2 domain

typedef short s16x8 __attribute__((ext_vector_type(8)));
typedef float f32x4 __attribute__((ext_vector_type(4)));

__device__ __forceinline__ unsigned short f2bf(float f) {
    unsigned u = __builtin_bit_cast(unsigned, f);
    u += 0x7fffu + ((u >> 16) & 1u);   // round-to-nearest-even (finite values only)
    return (unsigned short)(u >> 16);
}

__device__ __forceinline__ unsigned packbf2(float a, float b) {
    unsigned r;
    asm("v_cvt_pk_bf16_f32 %0, %1, %2" : "=v"(r) : "v"(a), "v"(b));
    return r;
}

// async global->LDS, 16B per lane; dst must be wave-uniform base (lane*16 added by HW)
__device__ __forceinline__ void gload16(const unsigned short* g, const unsigned short* l) {
    __builtin_amdgcn_global_load_lds(
        (const __attribute__((address_space(1))) void*)g,
        (__attribute__((address_space(3))) void*)l,
        16, 0, 0);
}

// K-style tile: rows of 128B, swizzle ((row&7)<<4)
__device__ __forceinline__ s16x8 kfr(const unsigned short* buf, int kr, int hb) {
    return *(const s16x8*)((const char*)buf + kr * 128 + (hb ^ ((kr & 7) << 4)));
}
// V tile: 64 rows x 256B, swizzle ((row&15)<<4)
__device__ __forceinline__ s16x8 vfr_(const unsigned short* buf, int vr, int kbyte) {
    return *(const s16x8*)((const char*)buf + vr * 256 + (kbyte ^ ((vr & 15) << 4)));
}

// ---------------------------------------------------------------------------
// Kernel 1: cast + transpose the four weight matrices to bf16, wt[n][k].
// LDS-staged 64x64 tile transpose (R13-proven).
// ---------------------------------------------------------------------------
__global__ __launch_bounds__(256)
void prep_weights(const float* __restrict__ wq, const float* __restrict__ wk,
                  const float* __restrict__ wv, const float* __restrict__ wo,
                  unsigned short* __restrict__ wt) {
    __shared__ unsigned short ts[64 * 72];   // [k][n] -> read back [n][k], pad 72

    const int mat = blockIdx.z;
    const float* w = (mat == 0) ? wq : (mat == 1) ? wk : (mat == 2) ? wv : wo;
    const int k0 = blockIdx.x * 64, n0 = blockIdx.y * 64;

    const int tid = threadIdx.x;
    const int kr = tid >> 2, nseg = (tid & 3) * 16;   // read: row k0+kr, 16 fp32 along n
    {
        const float* src = w + (size_t)(k0 + kr) * 512 + n0 + nseg;
        unsigned short tmp[16];
        #pragma unroll
        for (int j = 0; j < 16; j += 4) {
            float4 v = *(const float4*)(src + j);
            tmp[j] = f2bf(v.x); tmp[j+1] = f2bf(v.y); tmp[j+2] = f2bf(v.z); tmp[j+3] = f2bf(v.w);
        }
        #pragma unroll
        for (int j = 0; j < 16; ++j)
            ts[(nseg + j) * 72 + kr] = tmp[j];   // transpose into LDS
    }
    __syncthreads();

    const int nr = tid >> 2, kseg = (tid & 3) * 16;  // write: row n0+nr, 16 bf16 along k
    unsigned short* dst = wt + (size_t)mat * 262144 + (size_t)(n0 + nr) * 512 + k0 + kseg;
    *(s16x8*)dst       = *(const s16x8*)&ts[nr * 72 + kseg];
    *(s16x8*)(dst + 8) = *(const s16x8*)&ts[nr * 72 + kseg + 8];
}

// ---------------------------------------------------------------------------
// Kernel 2a: fused Q/K/V projection GEMM, 128x128 tile (R12-proven).
// ---------------------------------------------------------------------------
__global__ __launch_bounds__(256)
void qkv_gemm(const float* __restrict__ qx, const float* __restrict__ kx,
              const float* __restrict__ vx, const unsigned short* __restrict__ wtb,
              const float* __restrict__ bqp, const float* __restrict__ bkp,
              const float* __restrict__ bvp,
              unsigned short* __restrict__ qo, unsigned short* __restrict__ ko,
              unsigned short* __restrict__ vo) {
    __shared__ unsigned short smem[16384];   // 32KB: A [128][64] | B [128][64] (both swizzled)
    unsigned short* as_ = smem;              // 8192 elems
    unsigned short* bs_ = smem + 8192;

    const int z = blockIdx.z;
    const float* xin = (z == 0) ? qx : (z == 1) ? kx : vx;
    const unsigned short* wt = wtb + (size_t)z * 262144;
    const float* bias = (z == 0) ? bqp : (z == 1) ? bkp : bvp;
    const float oscale = (z == 0) ? QSCALE_ : 1.0f;

    const int tid  = threadIdx.x;
    const int wave = tid >> 6, lane = tid & 63;
    const int l15 = lane & 15, l4 = lane >> 4;
    const int wr = wave >> 1, wc = wave & 1;
    const int row0 = blockIdx.x * 128, col0 = blockIdx.y * 128;

    // A staging: thread t covers row t>>1, 32 fp32 (half = t&1)
    const int arow = tid >> 1, ahalf = tid & 1;
    const float* asrc0 = xin + (size_t)(row0 + arow) * 512 + ahalf * 32;

    // B staging: per-wave 4 gloads of 8 rows, pre-swizzled source column
    const int srow = lane >> 3;
    const int scol = 8 * ((lane & 7) ^ srow);
    const unsigned short* bsrc0 = wt + (size_t)(col0 + wave * 32 + srow) * 512 + scol;

    f32x4 acc[4][4] = {};

    for (int kt = 0; kt < 512; kt += 64) {
        #pragma unroll
        for (int i = 0; i < 4; ++i)
            gload16(bsrc0 + (size_t)i * 8 * 512 + kt, bs_ + (wave * 32 + i * 8) * 64);
        {
            const float* a = asrc0 + kt;
            #pragma unroll
            for (int j = 0; j < 4; ++j) {
                float4 v0 = *(const float4*)(a + j * 8);
                float4 v1 = *(const float4*)(a + j * 8 + 4);
                uint4 pk;
                pk.x = packbf2(v0.x, v0.y); pk.y = packbf2(v0.z, v0.w);
                pk.z = packbf2(v1.x, v1.y); pk.w = packbf2(v1.z, v1.w);
                *(uint4*)((char*)as_ + arow * 128 + ((ahalf * 64 + j * 16) ^ ((arow & 7) << 4))) = pk;
            }
        }
        __syncthreads();

        #pragma unroll
        for (int ks = 0; ks < 2; ++ks) {
            s16x8 af[4], bf[4];
            #pragma unroll
            for (int i = 0; i < 4; ++i) {
                af[i] = kfr(as_, wr * 64 + i * 16 + l15, ks * 64 + l4 * 16);
                bf[i] = kfr(bs_, wc * 64 + i * 16 + l15, ks * 64 + l4 * 16);
            }
            #pragma unroll
            for (int mf = 0; mf < 4; ++mf)
                #pragma unroll
                for (int nf = 0; nf < 4; ++nf)
                    acc[mf][nf] = __builtin_amdgcn_mfma_f32_16x16x32_bf16(af[mf], bf[nf], acc[mf][nf], 0, 0, 0);
        }
        __syncthreads();
    }

    if (z == 2) {
        // transpose-stage into smem: [128 n][128 m] bf16, swizzled rows of 256B
        #pragma unroll
        for (int nf = 0; nf < 4; ++nf) {
            const int nl = wc * 64 + nf * 16 + l15;
            float bv = bias[col0 + nl];
            #pragma unroll
            for (int mf = 0; mf < 4; ++mf) {
                uint2 pk;
                pk.x = packbf2(acc[mf][nf][0] + bv, acc[mf][nf][1] + bv);
                pk.y = packbf2(acc[mf][nf][2] + bv, acc[mf][nf][3] + bv);
                int mb = (wr * 64 + mf * 16 + l4 * 4) * 2;
                *(uint2*)((char*)smem + nl * 256 + (mb ^ ((nl & 7) << 4))) = pk;
            }
        }
        __syncthreads();
        const int nl = tid >> 1, half = tid & 1;
        const int c = col0 + nl, hh = c >> 6, hd = c & 63;
        const int bb = row0 >> 12, s0 = row0 & 4095;
        unsigned short* dst = vo + ((size_t)(bb * H_ + hh) * HD_ + hd) * S_ + s0 + half * 64;
        #pragma unroll
        for (int u = 0; u < 8; ++u)
            *(uint4*)((char*)dst + u * 16) =
                *(const uint4*)((char*)smem + nl * 256 + ((half * 128 + u * 16) ^ ((nl & 7) << 4)));
    } else {
        unsigned short* out = (z == 0) ? qo : ko;
        #pragma unroll
        for (int nf = 0; nf < 4; ++nf) {
            int c = col0 + wc * 64 + nf * 16 + l15;
            float bv = bias[c];
            #pragma unroll
            for (int mf = 0; mf < 4; ++mf)
                #pragma unroll
                for (int r = 0; r < 4; ++r) {
                    int t = row0 + wr * 64 + mf * 16 + l4 * 4 + r;
                    out[(size_t)t * 512 + c] = f2bf((acc[mf][nf][r] + bv) * oscale);
                }
        }
    }
}

// ---------------------------------------------------------------------------
// Kernel 2b: output projection GEMM, 128x128 tile (R13-proven).
// ---------------------------------------------------------------------------
__global__ __launch_bounds__(256)
void oproj_gemm(const unsigned short* __restrict__ xin, const unsigned short* __restrict__ wt,
                const float* __restrict__ bias, float* __restrict__ out) {
    __shared__ unsigned short smem[16384];   // A [128][64] | B [128][64] swizzled
    unsigned short* as_ = smem;
    unsigned short* bs_ = smem + 8192;

    const int tid  = threadIdx.x;
    const int wave = tid >> 6, lane = tid & 63;
    const int l15 = lane & 15, l4 = lane >> 4;
    const int wr = wave >> 1, wc = wave & 1;
    const int row0 = blockIdx.x * 128, col0 = blockIdx.y * 128;

    const int srow = lane >> 3;
    const int scol = 8 * ((lane & 7) ^ srow);
    const unsigned short* asrc0 = xin + (size_t)(row0 + wave * 32 + srow) * 512 + scol;
    const unsigned short* bsrc0 = wt + (size_t)(col0 + wave * 32 + srow) * 512 + scol;

    f32x4 acc[4][4] = {};

    for (int kt = 0; kt < 512; kt += 64) {
        #pragma unroll
        for (int i = 0; i < 4; ++i) {
            gload16(asrc0 + (size_t)i * 8 * 512 + kt, as_ + (wave * 32 + i * 8) * 64);
            gload16(bsrc0 + (size_t)i * 8 * 512 + kt, bs_ + (wave * 32 + i * 8) * 64);
        }
        __syncthreads();

        #pragma unroll
        for (int ks = 0; ks < 2; ++ks) {
            s16x8 af[4], bf[4];
            #pragma unroll
            for (int i = 0; i < 4; ++i) {
                af[i] = kfr(as_, wr * 64 + i * 16 + l15, ks * 64 + l4 * 16);
                bf[i] = kfr(bs_, wc * 64 + i * 16 + l15, ks * 64 + l4 * 16);
            }
            #pragma unroll
            for (int mf = 0; mf < 4; ++mf)
                #pragma unroll
                for (int nf = 0; nf < 4; ++nf)
                    acc[mf][nf] = __builtin_amdgcn_mfma_f32_16x16x32_bf16(af[mf], bf[nf], acc[mf][nf], 0, 0, 0);
        }
        __syncthreads();
    }

    #pragma unroll
    for (int nf = 0; nf < 4; ++nf) {
        int c = col0 + wc * 64 + nf * 16 + l15;
        float bv = bias[c];
        #pragma unroll
        for (int mf = 0; mf < 4; ++mf)
            #pragma unroll
            for (int r = 0; r < 4; ++r) {
                int t = row0 + wr * 64 + mf * 16 + l4 * 4 + r;
                out[(size_t)t * 512 + c] = acc[mf][nf][r] + bv;
            }
    }
}

// ---------------------------------------------------------------------------
// Kernel 3: fused attention (R11/R12/R13-proven flow, unified 80KB smem).
// Pass 1: KVBLK=256 double-buffered (16 barriers).
// Pass 2: KVBLK=128. NEW: counted `s_waitcnt vmcnt(16)` + raw s_barrier per
// chunk — waits only the 8 staging gloads (issue-order oldest), leaves the
// 16 weight stores in flight under the next chunk's compute.
// ---------------------------------------------------------------------------
__global__ __launch_bounds__(256)
void attn_kernel(const unsigned short* __restrict__ qb,
                 const unsigned short* __restrict__ kb,
                 const unsigned short* __restrict__ vt,
                 float* __restrict__ wout,          // weights tensor base [B,H,S,S]
                 unsigned short* __restrict__ ob) { // pre-projection output, bf16 [t][512]
    __shared__ unsigned short smem[40960];     // 80 KB, manually carved:
    // pass 2: K = smem[0 .. 16383] (2 x 8192), V = smem[16384 .. 32767] (2 x 8192),
    //         P strips = smem[32768 .. 40959] (4 waves x 2048)
    // pass 1: K256 = smem[0 .. 32767] (2 x 16384 = 2 x (256 rows x 64 elems))

    const int tid  = threadIdx.x;
    const int wave = tid >> 6, lane = tid & 63;
    const int l15 = lane & 15, l4 = lane >> 4;

    // XCD-aware swizzle (512 blocks, bijective)
    const int lid = blockIdx.x;
    const int wid = (lid & 7) * 64 + (lid >> 3);
    const int bh = wid >> 5;
    const int q0 = (wid & 31) * 128;
    const int b = bh >> 3, h = bh & 7;

    const int ksrow = lane >> 3;
    const int kscol = 8 * ((lane & 7) ^ ksrow);
    // pass-2 K staging base (wave owns 32 rows per 128-chunk)
    const unsigned short* kstg0 = kb + (size_t)(b * S_ + wave * 32 + ksrow) * 512 + h * 64 + kscol;
    // pass-1 K staging base (wave owns 64 rows per 256-chunk)
    const unsigned short* kstg1 = kb + (size_t)(b * S_ + wave * 64 + ksrow) * 512 + h * 64 + kscol;
    const int vsrow = lane >> 4;

#define KSTAGE1(c, bsel)                                                        \
    { _Pragma("unroll")                                                         \
      for (int i_ = 0; i_ < 8; ++i_)                                            \
          gload16(kstg1 + ((size_t)(c) * 256 + i_ * 8) * 512,                   \
                  smem + (bsel) * 16384 + (wave * 64 + i_ * 8) * 64); }

#define KSTAGE(c, bsel)                                                         \
    { _Pragma("unroll")                                                         \
      for (int i_ = 0; i_ < 4; ++i_)                                            \
          gload16(kstg0 + ((size_t)(c) * 128 + i_ * 8) * 512,                   \
                  smem + (bsel) * 8192 + (wave * 32 + i_ * 8) * 64); }

#define VSTAGE(c, bsel)                                                         \
    { _Pragma("unroll")                                                         \
      for (int i_ = 0; i_ < 4; ++i_) {                                          \
          int vrow_ = wave * 16 + i_ * 4 + vsrow;                               \
          int vcb_  = (lane & 15) ^ (i_ * 4 + vsrow);                           \
          gload16(vt + ((size_t)(bh * 64) + vrow_) * 4096 + (c) * 128 + vcb_ * 8, \
                  smem + 16384 + (bsel) * 8192 + (wave * 16 + i_ * 4) * 128); } }

    // Q fragments: 2 q-halves x 2 k-halves (pre-scaled by 0.125*log2e)
    s16x8 aq[2][2];
    #pragma unroll
    for (int qh = 0; qh < 2; ++qh) {
        const int t = b * S_ + q0 + wave * 32 + qh * 16 + l15;
        const unsigned short* qp = qb + (size_t)t * 512 + h * 64;
        aq[qh][0] = *(const s16x8*)(qp + l4 * 8);
        aq[qh][1] = *(const s16x8*)(qp + 32 + l4 * 8);
    }

    // ---------------- pass 1: per-lane denominators (KVBLK=256) ----------------
    float lsum[2] = {0.0f, 0.0f};
    KSTAGE1(0, 0);
    __syncthreads();

    for (int c = 0; c < 16; ++c) {
        const int cur = c & 1;
        if (c < 15) KSTAGE1(c + 1, cur ^ 1);
        const unsigned short* kcur = smem + cur * 16384;

        #pragma unroll
        for (int sub = 0; sub < 4; ++sub) {
            f32x4 sc[4][2] = {};
            __builtin_amdgcn_s_setprio(1);
            #pragma unroll
            for (int ks = 0; ks < 2; ++ks)
                #pragma unroll
                for (int kg = 0; kg < 4; ++kg) {
                    s16x8 kf = kfr(kcur, sub * 64 + kg * 16 + l15, ks * 64 + l4 * 16);
                    sc[kg][0] = __builtin_amdgcn_mfma_f32_16x16x32_bf16(kf, aq[0][ks], sc[kg][0], 0, 0, 0);
                    sc[kg][1] = __builtin_amdgcn_mfma_f32_16x16x32_bf16(kf, aq[1][ks], sc[kg][1], 0, 0, 0);
                }
            __builtin_amdgcn_s_setprio(0);
            #pragma unroll
            for (int kg = 0; kg < 4; ++kg)
                #pragma unroll
                for (int r = 0; r < 4; ++r) {
                    lsum[0] += __builtin_amdgcn_exp2f(sc[kg][0][r]);
                    lsum[1] += __builtin_amdgcn_exp2f(sc[kg][1][r]);
                }
        }
        __syncthreads();
    }

    #pragma unroll
    for (int qh = 0; qh < 2; ++qh) {
        lsum[qh] += __shfl_xor(lsum[qh], 16);
        lsum[qh] += __shfl_xor(lsum[qh], 32);
    }
    const float off[2] = { -__builtin_amdgcn_logf(lsum[0]),
                           -__builtin_amdgcn_logf(lsum[1]) };

    // ---------------- pass 2: weights out + O accumulation (KVBLK=128) --------
    f32x4 ao[2][4] = {};
    float* wbase = wout + ((size_t)bh * S_ + q0 + wave * 32) * S_;
    unsigned short* strip = smem + 32768 + wave * 2048;

    KSTAGE(0, 0); VSTAGE(0, 0);
    __syncthreads();

    for (int c = 0; c < 32; ++c) {
        const int cur = c & 1;
        if (c < 31) { KSTAGE(c + 1, cur ^ 1); VSTAGE(c + 1, cur ^ 1); }
        __builtin_amdgcn_sched_barrier(0);   // pin gload issue before compute/stores
        const unsigned short* kcur = smem + cur * 8192;
        const unsigned short* vcur = smem + 16384 + cur * 8192;

        #pragma unroll
        for (int sub = 0; sub < 2; ++sub) {
            f32x4 sc[4][2] = {};
            __builtin_amdgcn_s_setprio(1);
            #pragma unroll
            for (int ks = 0; ks < 2; ++ks)
                #pragma unroll
                for (int kg = 0; kg < 4; ++kg) {
                    s16x8 kf = kfr(kcur, sub * 64 + kg * 16 + l15, ks * 64 + l4 * 16);
                    sc[kg][0] = __builtin_amdgcn_mfma_f32_16x16x32_bf16(kf, aq[0][ks], sc[kg][0], 0, 0, 0);
                    sc[kg][1] = __builtin_amdgcn_mfma_f32_16x16x32_bf16(kf, aq[1][ks], sc[kg][1], 0, 0, 0);
                }
            __builtin_amdgcn_s_setprio(0);

            // normalized weights: plain f32x4 stores + packed bf16 strip
            #pragma unroll
            for (int qh = 0; qh < 2; ++qh) {
                float* wrow = wbase + (size_t)(qh * 16 + l15) * S_ + c * 128 + sub * 64;
                const int q = qh * 16 + l15;
                #pragma unroll
                for (int kg = 0; kg < 4; ++kg) {
                    f32x4 w;
                    #pragma unroll
                    for (int r = 0; r < 4; ++r)
                        w[r] = __builtin_amdgcn_exp2f(sc[kg][qh][r] + off[qh]);
                    *(f32x4*)(wrow + kg * 16 + l4 * 4) = w;
                    uint2 pk;
                    pk.x = packbf2(w[0], w[1]);
                    pk.y = packbf2(w[2], w[3]);
                    *(uint2*)((char*)strip + q * 128 + ((kg * 32 + l4 * 8) ^ ((q & 7) << 4))) = pk;
                }
            }

            // PV: A = P strip frags (wave-private), B = V frags (reused 2x)
            __builtin_amdgcn_s_setprio(1);
            #pragma unroll
            for (int ks = 0; ks < 2; ++ks) {
                s16x8 pa0 = *(const s16x8*)((const char*)strip + l15 * 128
                               + ((ks * 64 + l4 * 16) ^ ((l15 & 7) << 4)));
                s16x8 pa1 = *(const s16x8*)((const char*)strip + (16 + l15) * 128
                               + ((ks * 64 + l4 * 16) ^ ((l15 & 7) << 4)));
                #pragma unroll
                for (int ng = 0; ng < 4; ++ng) {
                    s16x8 vf = vfr_(vcur, ng * 16 + l15, sub * 128 + ks * 64 + l4 * 16);
                    ao[0][ng] = __builtin_amdgcn_mfma_f32_16x16x32_bf16(pa0, vf, ao[0][ng], 0, 0, 0);
                    ao[1][ng] = __builtin_amdgcn_mfma_f32_16x16x32_bf16(pa1, vf, ao[1][ng], 0, 0, 0);
                }
            }
            __builtin_amdgcn_s_setprio(0);
        }

        // counted drain: oldest outstanding (old stores + this chunk's 8 gloads)
        // complete; this chunk's 16 weight stores stay in flight across the barrier.
        if (c < 31) {
            __builtin_amdgcn_sched_barrier(0);
            asm volatile("s_waitcnt vmcnt(16)" ::: "memory");
            __builtin_amdgcn_s_barrier();
            __builtin_amdgcn_sched_barrier(0);
        }
    }

    // store O tile (pre-projection) as bf16 [t][512] — reads no LDS
    #pragma unroll
    for (int qg = 0; qg < 2; ++qg)
        #pragma unroll
        for (int ng = 0; ng < 4; ++ng) {
            int hd = ng * 16 + l15;
            #pragma unroll
            for (int r = 0; r < 4; ++r) {
                int t = b * S_ + q0 + wave * 32 + qg * 16 + l4 * 4 + r;
                ob[(size_t)t * 512 + h * 64 + hd] = f2bf(ao[qg][ng][r]);
            }
        }
#undef KSTAGE1
#undef KSTAGE
#undef VSTAGE
}

// ---------------------------------------------------------------------------
// Launch
// ---------------------------------------------------------------------------
extern "C" void kernel_launch(void* const* d_in, const int* in_sizes, int n_in,
                              void* d_out, int out_size, void* d_ws, size_t ws_size,
                              hipStream_t stream) {
    (void)in_sizes; (void)n_in; (void)out_size; (void)ws_size;

    const float* query = (const float*)d_in[0];
    const float* key_  = (const float*)d_in[1];
    const float* value = (const float*)d_in[2];
    const float* wq = (const float*)d_in[3];
    const float* bq = (const float*)d_in[4];
    const float* wk = (const float*)d_in[5];
    const float* bk = (const float*)d_in[6];
    const float* wv = (const float*)d_in[7];
    const float* bv = (const float*)d_in[8];
    const float* wo = (const float*)d_in[9];
    const float* bo = (const float*)d_in[10];
    float* out = (float*)d_out;

    // workspace: wt 2MB | qb 8MB | kb 8MB | vt 8MB | ob 8MB
    char* ws = (char*)d_ws;
    unsigned short* wt = (unsigned short*)(ws);
    unsigned short* qb = (unsigned short*)(ws + 2097152);
    unsigned short* kb = (unsigned short*)(ws + 2097152 + 1 * 8388608);
    unsigned short* vt = (unsigned short*)(ws + 2097152 + 2 * 8388608);
    unsigned short* ob = (unsigned short*)(ws + 2097152 + 3 * 8388608);

    hipLaunchKernelGGL(prep_weights, dim3(8, 8, 4), dim3(256), 0, stream, wq, wk, wv, wo, wt);

    hipLaunchKernelGGL(qkv_gemm, dim3(64, 4, 3), dim3(256), 0, stream,
                       query, key_, value, wt, bq, bk, bv, qb, kb, vt);

    hipLaunchKernelGGL(attn_kernel, dim3(512), dim3(256), 0, stream,
                       qb, kb, vt, out + 4194304, ob);

    hipLaunchKernelGGL(oproj_gemm, dim3(64, 4), dim3(256), 0, stream,
                       ob, wt + 3 * 262144, bo, out);
}